// Round 2
// baseline (349.010 us; speedup 1.0000x reference)
//
#include <hip/hip_runtime.h>
#include <hip/hip_bf16.h>

// Problem dims (fixed by reference)
//   B=128, T=256, D_MODEL=128, D_INNER=256, D_STATE=16, D_CONV=4, DT_RANK=8
// I/O dtype: float32. MFMA bf16 for in_proj/out_proj/x_proj. R13:
//  - scan7: occupancy remap. R12's register double-buffer was defeated by the
//    scheduler (VGPR 92, not ~185 — loads sunk to point-of-use). Root cause of
//    the latency exposure is structural: 4 lanes/(b,d) x 4 states = 2048 waves
//    = 2 waves/SIMD grid cap. scan7 uses 8 lanes/(b,d) x 2 states -> 4096
//    waves = 4 waves/SIMD (16 waves/CU, 32KB LDS -> grid-exact 4 blocks/CU).
//    Per-step: 11 VALU + 3 shfl (was 15 + 2); S reads become ds_read_b64.
//    u/d/z chunk dbuf kept; 8 q-lanes share u/d addresses (coalescer dedups).
// Outputs: h (128,128,128) then x_skip (128,256,128), fp32, concatenated.

typedef __attribute__((ext_vector_type(8))) short bf16x8;
typedef __attribute__((ext_vector_type(4))) short bf16x4;
typedef __attribute__((ext_vector_type(4))) float f32x4;
using bf16 = __hip_bfloat16;

static __device__ __forceinline__ short f2s(float v) {
  union { bf16 b; short s; } u; u.b = (bf16)v; return u.s;
}
static __device__ __forceinline__ float s2f(short s) {
  union { short s; bf16 b; } u; u.s = s; return (float)u.b;
}

// ---------------------------------------------------------------------------
// cvt_x: x fp32 -> bf16 xb AND x_skip passthrough (out1), 4 elems/thread.
// ---------------------------------------------------------------------------
__global__ __launch_bounds__(256) void cvt_x(const float* __restrict__ x,
                                             short* __restrict__ xb,
                                             float* __restrict__ out1) {
  int i = (blockIdx.x * 256 + threadIdx.x) * 4;
  f32x4 v = *(const f32x4*)(x + i);
  bf16x4 o;
  o[0] = f2s(v[0]); o[1] = f2s(v[1]); o[2] = f2s(v[2]); o[3] = f2s(v[3]);
  *(bf16x4*)(xb + i) = o;
  *(f32x4*)(out1 + i) = v;
}

// ---------------------------------------------------------------------------
// Weight prep: ipw(512x128)->bf16 (ws), opw(128x256)->bf16 (ws),
// down_w (co,ci,k) -> WT[(k*128+ci)*128+co] fp32 (out0 region),
// x_proj_w -> wxb (64x256 bf16, rows 40..63 zero; out0 region).
// out0 staging is safe: ln_k writes out0 LAST, after all consumers.
// ---------------------------------------------------------------------------
__global__ __launch_bounds__(256) void prep_w(const float* __restrict__ ipw,
                                              const float* __restrict__ opw,
                                              const float* __restrict__ dw,
                                              const float* __restrict__ xpw,
                                              short* __restrict__ ipwb,
                                              short* __restrict__ opwb,
                                              float* __restrict__ wt,
                                              short* __restrict__ wxb) {
  int idx = blockIdx.x * 256 + threadIdx.x;   // 0 .. 163839
  if (idx < 65536) {
    ipwb[idx] = f2s(ipw[idx]);
  } else if (idx < 98304) {
    int j = idx - 65536;
    opwb[j] = f2s(opw[j]);
  } else if (idx < 147456) {
    int j = idx - 98304;          // (k*128+ci)*128 + co
    int co = j & 127;
    int p  = j >> 7;              // k*128+ci
    int k  = p >> 7;
    int ci = p & 127;
    wt[j] = dw[(co * 128 + ci) * 3 + k];
  } else {
    int j = idx - 147456;         // n*256 + k
    int n = j >> 8;
    wxb[j] = (n < 40) ? f2s(xpw[j]) : (short)0;
  }
}

// ---------------------------------------------------------------------------
// MFMA GEMM: C = A(MxK bf16) @ W(NxK bf16)^T. Block 256thr/4 waves, tile
// 64m x 64n, wave = 16 rows x 4 n-frags. mfma_f32_16x16x32_bf16 layouts:
//   A/B frag: row(lane&15), k = (lane>>4)*8 + j
//   C/D frag: col(lane&15), row = (lane>>4)*4 + reg
// MODE 0: fp32 store, ldc=N. MODE 1 (in_proj): col<256 -> bf16 xcpre,
// col>=256 -> bf16 silu -> zact.
// ---------------------------------------------------------------------------
template<int N, int K, int MODE>
__global__ __launch_bounds__(256) void mgemm(const short* __restrict__ A,
                                             const short* __restrict__ W,
                                             float* __restrict__ C,
                                             short* __restrict__ xcpre,
                                             short* __restrict__ zact) {
  const int m_base = blockIdx.x * 64;
  const int n_base = blockIdx.y * 64;
  const int wave = threadIdx.x >> 6;
  const int lane = threadIdx.x & 63;
  const int r16  = lane & 15;
  const int quad = lane >> 4;
  f32x4 acc[4] = {};
  const short* Ap = A + (size_t)(m_base + wave * 16 + r16) * K + quad * 8;
  const short* Wp = W + (size_t)(n_base + r16) * K + quad * 8;
#pragma unroll
  for (int k0 = 0; k0 < K; k0 += 32) {
    bf16x8 a = *(const bf16x8*)(Ap + k0);
#pragma unroll
    for (int j = 0; j < 4; ++j) {
      bf16x8 b = *(const bf16x8*)(Wp + (size_t)j * 16 * K + k0);
      acc[j] = __builtin_amdgcn_mfma_f32_16x16x32_bf16(a, b, acc[j], 0, 0, 0);
    }
  }
#pragma unroll
  for (int j = 0; j < 4; ++j) {
    const int col = n_base + j * 16 + r16;
#pragma unroll
    for (int r = 0; r < 4; ++r) {
      const int row = m_base + wave * 16 + quad * 4 + r;
      if (MODE == 0) {
        C[(size_t)row * N + col] = acc[j][r];
      } else {
        if (col < 256) {
          xcpre[(size_t)row * 256 + col] = f2s(acc[j][r]);
        } else {
          float v = acc[j][r];
          zact[(size_t)row * 256 + (col - 256)] = f2s(v / (1.f + __expf(-v)));
        }
      }
    }
  }
}

// ---------------------------------------------------------------------------
// conv_silu2: depthwise causal conv (width 4) + bias + silu. Block = (b,
// 64-d tile), 256 thr = 64 d-lanes x 4 t-groups of 64. Each thread runs its
// t-range serially (coalesced 128B/wave input reads, 3-tap history in regs).
// Emits xcb (b,t,d) for the x_proj GEMM and, via LDS transpose, xcT (b,d,t)
// with 1KB-coalesced b128 stores.
// ---------------------------------------------------------------------------
__global__ __launch_bounds__(256) void conv_silu2(const short* __restrict__ xcpre,
                                                  const float* __restrict__ cw,
                                                  const float* __restrict__ cb,
                                                  short* __restrict__ xcb,
                                                  short* __restrict__ xcT) {
  const int b  = blockIdx.x >> 2;
  const int dt = (blockIdx.x & 3) * 64;
  const int tg = threadIdx.x >> 6;
  const int dl = threadIdx.x & 63;
  const int d  = dt + dl;
  const int t0 = tg * 64;
  __shared__ short L[64][264];                 // [d][t] bf16, stride 264 (16B-aligned)
  const float w0 = cw[d * 4], w1 = cw[d * 4 + 1], w2 = cw[d * 4 + 2], w3 = cw[d * 4 + 3];
  const float bias = cb[d];
  const size_t base = (size_t)b * 65536 + d;   // xcpre[(b,t,d)] = base + t*256
  float p0 = (t0 >= 3) ? s2f(xcpre[base + (size_t)(t0 - 3) * 256]) : 0.f;
  float p1 = (t0 >= 2) ? s2f(xcpre[base + (size_t)(t0 - 2) * 256]) : 0.f;
  float p2 = (t0 >= 1) ? s2f(xcpre[base + (size_t)(t0 - 1) * 256]) : 0.f;
  for (int t = t0; t < t0 + 64; ++t) {
    float cur = s2f(xcpre[base + (size_t)t * 256]);
    float acc = bias + p0 * w0 + p1 * w1 + p2 * w2 + cur * w3;
    short s = f2s(acc / (1.f + __expf(-acc)));
    xcb[base + (size_t)t * 256] = s;           // coalesced per t
    L[dl][t] = s;
    p0 = p1; p1 = p2; p2 = cur;
  }
  __syncthreads();
  // transpose write-out: per round, wave covers 2 full d-rows -> 1KB contig
#pragma unroll
  for (int r8 = 0; r8 < 8; ++r8) {
    const int dw = r8 * 8 + (threadIdx.x >> 5);
    const int tc = threadIdx.x & 31;
    bf16x8 v = *(const bf16x8*)(&L[dw][tc * 8]);
    *(bf16x8*)(xcT + ((size_t)b * 256 + dt + dw) * 256 + tc * 8) = v;
  }
}

// ---------------------------------------------------------------------------
// repack: delta = softplus(dt . dt_proj_w[d] + b[d]) and z-transpose.
// Same block/tile structure as conv_silu2; emits dT,zT in (b,d,t) bf16.
// ---------------------------------------------------------------------------
__global__ __launch_bounds__(256) void repack(const float* __restrict__ xdbl,
                                              const short* __restrict__ zact,
                                              const float* __restrict__ dtw,
                                              const float* __restrict__ dtb,
                                              short* __restrict__ dT,
                                              short* __restrict__ zT) {
  const int b  = blockIdx.x >> 2;
  const int dt = (blockIdx.x & 3) * 64;
  const int tg = threadIdx.x >> 6;
  const int dl = threadIdx.x & 63;
  const int d  = dt + dl;
  const int t0 = tg * 64;
  __shared__ short Ld[64][264], Lz[64][264];   // 2 x 33,792 B
  float wd[8];
#pragma unroll
  for (int j = 0; j < 8; ++j) wd[j] = dtw[d * 8 + j];
  const float bd = dtb[d];
  for (int t = t0; t < t0 + 64; ++t) {
    const float* r = xdbl + (size_t)(b * 256 + t) * 64;
    float acc = bd;
#pragma unroll
    for (int j = 0; j < 8; ++j) acc += r[j] * wd[j];
    const float delta = (acc > 20.f) ? acc : __logf(1.f + __expf(acc));
    Ld[dl][t] = f2s(delta);
    Lz[dl][t] = zact[(size_t)b * 65536 + (size_t)t * 256 + d];
  }
  __syncthreads();
#pragma unroll
  for (int r8 = 0; r8 < 8; ++r8) {
    const int dw = r8 * 8 + (threadIdx.x >> 5);
    const int tc = threadIdx.x & 31;
    const size_t o = ((size_t)b * 256 + dt + dw) * 256 + tc * 8;
    *(bf16x8*)(dT + o) = *(const bf16x8*)(&Ld[dw][tc * 8]);
    *(bf16x8*)(zT + o) = *(const bf16x8*)(&Lz[dw][tc * 8]);
  }
}

// ---------------------------------------------------------------------------
// scan7: state-parallel selective scan, occupancy-remapped. Block = (b, group
// of 32 d), 256 thr = 32 d x 8 lanes; lane owns 2 of 16 states, serial T=256.
// 4096 waves total = 4 waves/SIMD (was 2): latency hiding doubles; per-step
// VALU drops to ~11 ops + 3 shfl. S (B/C fp32) in LDS from xdbl, ds_read_b64
// per operand (8 distinct addrs/wave, broadcast, conflict-free). u/delta/z
// remain chunk-double-buffered bf16x8 (8 q-lanes share addresses -> coalescer
// dedups). zT load exec-masked to q==0 (sole consumer). exp2 w/ log2e in A.
// __launch_bounds__(256,4): VGPR cap 128 (est. ~70, no spill).
// ---------------------------------------------------------------------------
__global__ __launch_bounds__(256, 4) void scan7(const float* __restrict__ xdbl,
                                                const short* __restrict__ xcT,
                                                const short* __restrict__ dT,
                                                const short* __restrict__ zT,
                                                const float* __restrict__ alog,
                                                const float* __restrict__ Dp,
                                                short* __restrict__ yb) {
  const int g = blockIdx.x & 7;
  const int b = blockIdx.x >> 3;
  const int q = threadIdx.x & 7;              // 8 lanes per d, 2 states each
  const int d = g * 32 + (threadIdx.x >> 3);
  const size_t rb = (size_t)b * 256;
  __shared__ float S[256][32];                // B(16)|C(16) fp32 per t, 32 KB
  for (int i = threadIdx.x; i < 2048; i += 256) {
    int row = i >> 3, c4 = i & 7;
    f32x4 v = *(const f32x4*)(xdbl + (rb + row) * 64 + 8 + c4 * 4);
    *(f32x4*)(&S[row][c4 * 4]) = v;
  }
  float A0 = -__expf(alog[d * 16 + q * 2])     * 1.44269504089f;
  float A1 = -__expf(alog[d * 16 + q * 2 + 1]) * 1.44269504089f;
  const float Dv = Dp[d];
  float h0 = 0.f, h1 = 0.f;
  const size_t tb = ((size_t)b * 256 + d) * 256;   // t-row base (b,d,t)
  bf16x8 ucur = *(const bf16x8*)(xcT + tb);
  bf16x8 dcur = *(const bf16x8*)(dT + tb);
  bf16x8 zcur = {};
  if (q == 0) zcur = *(const bf16x8*)(zT + tb);
  __syncthreads();
  for (int c = 0; c < 32; ++c) {
    bf16x8 unx = ucur, dnx = dcur, znx = zcur;
    if (c + 1 < 32) {
      unx = *(const bf16x8*)(xcT + tb + (c + 1) * 8);
      dnx = *(const bf16x8*)(dT + tb + (c + 1) * 8);
      if (q == 0) znx = *(const bf16x8*)(zT + tb + (c + 1) * 8);
    }
#pragma unroll
    for (int tt = 0; tt < 8; ++tt) {
      const int t = c * 8 + tt;
      const float2 Bq = *(const float2*)(&S[t][q * 2]);
      const float2 Cq = *(const float2*)(&S[t][16 + q * 2]);
      const float delta = s2f(dcur[tt]);
      const float u     = s2f(ucur[tt]);
      const float du    = delta * u;
      const float dA0 = __builtin_amdgcn_exp2f(delta * A0);
      const float dA1 = __builtin_amdgcn_exp2f(delta * A1);
      h0 = dA0 * h0 + du * Bq.x;
      h1 = dA1 * h1 + du * Bq.y;
      float yt = h0 * Cq.x + h1 * Cq.y;
      yt += __shfl_xor(yt, 1);
      yt += __shfl_xor(yt, 2);
      yt += __shfl_xor(yt, 4);
      if (q == 0)
        yb[(rb + t) * 256 + d] = f2s((yt + u * Dv) * s2f(zcur[tt]));
    }
    ucur = unx; dcur = dnx; zcur = znx;
  }
}

// ---------------------------------------------------------------------------
// Fused strided down-conv: hd[b,to,co] = sum_{k,ci} h1[b,2to+k-1,ci]*w[co,ci,k]
// + db[co]. Block = (b, 8 'to'), 128 threads; 17 h1 rows in LDS.
// ---------------------------------------------------------------------------
__global__ __launch_bounds__(128) void down_k(const float* __restrict__ h1,
                                              const float* __restrict__ wt,
                                              const float* __restrict__ db,
                                              float* __restrict__ hd) {
  const int b   = blockIdx.x >> 4;
  const int to0 = (blockIdx.x & 15) * 8;
  const int co  = threadIdx.x;
  __shared__ float hs[17][128];
  const int tbase = 2 * to0 - 1;
#pragma unroll
  for (int i = 0; i < 17; ++i) {
    int t = tbase + i;
    hs[i][co] = (t >= 0 && t < 256) ? h1[(size_t)(b * 256 + t) * 128 + co] : 0.f;
  }
  __syncthreads();
  float acc[8];
  const float bias = db[co];
#pragma unroll
  for (int r = 0; r < 8; ++r) acc[r] = bias;
  for (int j = 0; j < 384; ++j) {
    float w = wt[j * 128 + co];
    int k = j >> 7, ci = j & 127;
#pragma unroll
    for (int r = 0; r < 8; ++r) acc[r] += hs[2 * r + k][ci] * w;
  }
#pragma unroll
  for (int r = 0; r < 8; ++r)
    hd[(size_t)(b * 128 + to0 + r) * 128 + co] = acc[r];
}

// ---------------------------------------------------------------------------
// LayerNorm over last dim (128), eps 1e-5. One wave per row, 2 cols/thread.
// ---------------------------------------------------------------------------
__global__ __launch_bounds__(64) void ln_k(const float* __restrict__ hd,
                                           const float* __restrict__ g,
                                           const float* __restrict__ be,
                                           float* __restrict__ out) {
  int row = blockIdx.x;
  const float* r = hd + (size_t)row * 128;
  float v0 = r[threadIdx.x];
  float v1 = r[threadIdx.x + 64];
  float s = v0 + v1;
#pragma unroll
  for (int off = 32; off; off >>= 1) s += __shfl_xor(s, off);
  float mu = s * (1.0f / 128.0f);
  float d0 = v0 - mu, d1 = v1 - mu;
  float vs = d0 * d0 + d1 * d1;
#pragma unroll
  for (int off = 32; off; off >>= 1) vs += __shfl_xor(vs, off);
  float rstd = rsqrtf(vs * (1.0f / 128.0f) + 1e-5f);
  out[(size_t)row * 128 + threadIdx.x]      = d0 * rstd * g[threadIdx.x] + be[threadIdx.x];
  out[(size_t)row * 128 + threadIdx.x + 64] = d1 * rstd * g[threadIdx.x + 64] + be[threadIdx.x + 64];
}

// ---------------------------------------------------------------------------
// Workspace layout (bytes), peak 92,471,296 == proven-safe bound:
//   [0,16M)      xcpre bf16 (in_proj->conv) -> yb bf16 (scan->out_proj)
//                -> hd fp32 8.4MB (down_k->ln)
//   [16M,32M)    xcT bf16 (conv->scan)
//   [32M,48M)    zact bf16 (in_proj->repack)
//   [48M,64M)    xcb bf16 (conv->xproj) -> dT bf16 (repack->scan)
//                -> h1 fp32 (out_proj->down_k)
//   [64M,72M)    xdbl fp32 (xproj->scan)
//   [72M,88M)    xb bf16 8.4MB (cvt->in_proj) -> zT bf16 (repack->scan)
//   [88M,88.2M)  ipwb | opwb bf16  (ends exactly at 92,471,296)
// d_out staging: wt (192KB fp32) + wxb (32KB bf16) in OUT0 region
// (ln_k writes out0 LAST); out1 written once by cvt_x.
// ---------------------------------------------------------------------------
static const size_t O_XCPRE = 0;            // also yb, then hd
static const size_t O_XCT   = 16777216;
static const size_t O_ZACT  = 33554432;
static const size_t O_XCB   = 50331648;     // also dT, then h1
static const size_t O_XDBL  = 67108864;
static const size_t O_XB    = 75497472;     // also zT (16,777,216 B)
static const size_t O_IPWB  = 92274688;     // 131,072 B
static const size_t O_OPWB  = 92405760;     //  65,536 B -> end 92,471,296

extern "C" void kernel_launch(void* const* d_in, const int* in_sizes, int n_in,
                              void* d_out, int out_size, void* d_ws, size_t ws_size,
                              hipStream_t stream) {
  const float* x    = (const float*)d_in[0];
  const float* ipw  = (const float*)d_in[1];
  const float* cw   = (const float*)d_in[2];
  const float* cb   = (const float*)d_in[3];
  const float* xpw  = (const float*)d_in[4];
  const float* dtw  = (const float*)d_in[5];
  const float* dtb  = (const float*)d_in[6];
  const float* alog = (const float*)d_in[7];
  const float* Dp   = (const float*)d_in[8];
  const float* opw  = (const float*)d_in[9];
  const float* dw   = (const float*)d_in[10];
  const float* db   = (const float*)d_in[11];
  const float* lng  = (const float*)d_in[12];
  const float* lnb  = (const float*)d_in[13];

  char*  ws     = (char*)d_ws;
  short* xcpre  = (short*)(ws + O_XCPRE);
  short* yb     = (short*)(ws + O_XCPRE);  // alias (xcpre dead after conv)
  float* hd     = (float*)(ws + O_XCPRE);  // alias (yb dead after out_proj)
  short* xcT    = (short*)(ws + O_XCT);
  short* zact   = (short*)(ws + O_ZACT);
  short* xcb    = (short*)(ws + O_XCB);
  short* dT     = (short*)(ws + O_XCB);    // alias (xcb dead after xproj)
  float* h1     = (float*)(ws + O_XCB);    // alias (dT dead after scan)
  float* xdbl   = (float*)(ws + O_XDBL);
  short* xb     = (short*)(ws + O_XB);
  short* zT     = (short*)(ws + O_XB);     // alias (xb dead after in_proj)
  short* ipwb   = (short*)(ws + O_IPWB);
  short* opwb   = (short*)(ws + O_OPWB);
  float* out    = (float*)d_out;
  float* wt     = out;                     // out0 region; ln_k writes last
  short* wxb    = (short*)(out + 49152);
  float* out1   = out + 2097152;

  // 0. x -> bf16 + x_skip passthrough; weight prep
  cvt_x<<<4096, 256, 0, stream>>>(x, xb, out1);
  prep_w<<<640, 256, 0, stream>>>(ipw, opw, dw, xpw, ipwb, opwb, wt, wxb);
  // 1. in_proj MFMA (32768x512, K=128) -> bf16 xcpre + bf16 silu(z)
  mgemm<512, 128, 1><<<dim3(512, 8), 256, 0, stream>>>(
      xb, ipwb, nullptr, xcpre, zact);
  // 2. depthwise causal conv + silu -> xcb (b,t,d) + xcT (b,d,t)
  conv_silu2<<<512, 256, 0, stream>>>(xcpre, cw, cb, xcb, xcT);
  // 3. x_dbl MFMA: xcb @ wxb^T (32768x64, K=256) -> fp32 xdbl
  mgemm<64, 256, 0><<<dim3(512, 1), 256, 0, stream>>>(
      xcb, wxb, xdbl, nullptr, nullptr);
  // 4. delta + z transpose -> dT, zT (b,d,t)
  repack<<<512, 256, 0, stream>>>(xdbl, zact, dtw, dtb, dT, zT);
  // 5. state-parallel scan (4 waves/SIMD) -> yb bf16
  scan7<<<1024, 256, 0, stream>>>(xdbl, xcT, dT, zT, alog, Dp, yb);
  // 6. out_proj MFMA: h1 = y @ out_proj_w^T (32768x128, K=256), fp32 out
  mgemm<128, 256, 0><<<dim3(512, 2), 256, 0, stream>>>(
      yb, opwb, h1, nullptr, nullptr);
  // 7. fused strided down-conv -> hd (16384x128, ws)
  down_k<<<2048, 128, 0, stream>>>(h1, wt, db, hd);
  // 8. LayerNorm -> output 0 (overwrites wt/wxb staging — consumed already)
  ln_k<<<16384, 64, 0, stream>>>(hd, lng, lnb, out);
}

// Round 3
// 298.861 us; speedup vs baseline: 1.1678x; 1.1678x over previous
//
#include <hip/hip_runtime.h>
#include <hip/hip_bf16.h>

// Problem dims (fixed by reference)
//   B=128, T=256, D_MODEL=128, D_INNER=256, D_STATE=16, D_CONV=4, DT_RANK=8
// I/O dtype: float32. MFMA bf16 for in_proj/x_proj/fused-tail. R14:
//  - scan: REVERT to scan6 (R1, 61.7us). scan7's 8-lane remap raised occupancy
//    19->39% but grew dynamic instructions 1.65x -> 74.5us. Net negative.
//  - NEW od_k: out_proj + strided down-conv + bias + LayerNorm fused into ONE
//    MFMA GEMM over K=768: hd[b,to,co] = sum_k y[b,2to+k-1,:] . G_k[co,:],
//    G_k = dwn_k @ opw (precomputed by g_prep, fp32 dot -> bf16). Replaces
//    out_proj mgemm (~8us) + down_k (VALU-bound ~20us: 1.6G scalar FMA with
//    1:1 ds_read) + ln_k (16384 tiny blocks ~5us) and kills the 16MB h1 and
//    8MB hd round-trips. LN fused in epilogue via 16-lane shfl reductions.
// Outputs: h (128,128,128) then x_skip (128,256,128), fp32, concatenated.

typedef __attribute__((ext_vector_type(8))) short bf16x8;
typedef __attribute__((ext_vector_type(4))) short bf16x4;
typedef __attribute__((ext_vector_type(4))) float f32x4;
using bf16 = __hip_bfloat16;

static __device__ __forceinline__ short f2s(float v) {
  union { bf16 b; short s; } u; u.b = (bf16)v; return u.s;
}
static __device__ __forceinline__ float s2f(short s) {
  union { short s; bf16 b; } u; u.s = s; return (float)u.b;
}

// ---------------------------------------------------------------------------
// cvt_x: x fp32 -> bf16 xb AND x_skip passthrough (out1), 4 elems/thread.
// ---------------------------------------------------------------------------
__global__ __launch_bounds__(256) void cvt_x(const float* __restrict__ x,
                                             short* __restrict__ xb,
                                             float* __restrict__ out1) {
  int i = (blockIdx.x * 256 + threadIdx.x) * 4;
  f32x4 v = *(const f32x4*)(x + i);
  bf16x4 o;
  o[0] = f2s(v[0]); o[1] = f2s(v[1]); o[2] = f2s(v[2]); o[3] = f2s(v[3]);
  *(bf16x4*)(xb + i) = o;
  *(f32x4*)(out1 + i) = v;
}

// ---------------------------------------------------------------------------
// Weight prep: ipw(512x128)->bf16 (ws), x_proj_w -> wxb (64x256 bf16, rows
// 40..63 zero; staged in out0 -- safe: od_k writes out0 LAST, after wxb use).
// ---------------------------------------------------------------------------
__global__ __launch_bounds__(256) void prep_w(const float* __restrict__ ipw,
                                              const float* __restrict__ xpw,
                                              short* __restrict__ ipwb,
                                              short* __restrict__ wxb) {
  int idx = blockIdx.x * 256 + threadIdx.x;   // 0 .. 81919
  if (idx < 65536) {
    ipwb[idx] = f2s(ipw[idx]);
  } else {
    int j = idx - 65536;          // n*256 + k
    int n = j >> 8;
    wxb[j] = (n < 40) ? f2s(xpw[j]) : (short)0;
  }
}

// ---------------------------------------------------------------------------
// g_prep: fused tail weight G_k[co,e] = sum_dm dwn[co,dm,k] * opw[dm,e].
// Block = (k*128+co), 256 thr = e. fp32 dot, bf16 store. 12.6 MFLOP, tiny.
// G lives in the ipwb tail region (ipwb dead after in_proj; launched after).
// ---------------------------------------------------------------------------
__global__ __launch_bounds__(256) void g_prep(const float* __restrict__ dwn,
                                              const float* __restrict__ opw,
                                              short* __restrict__ G) {
  const int k  = blockIdx.x >> 7;
  const int co = blockIdx.x & 127;
  const int e  = threadIdx.x;
  float acc = 0.f;
  for (int dm = 0; dm < 128; ++dm) {
    acc += dwn[(co * 128 + dm) * 3 + k] * opw[dm * 256 + e];
  }
  G[(size_t)(k * 128 + co) * 256 + e] = f2s(acc);
}

// ---------------------------------------------------------------------------
// MFMA GEMM: C = A(MxK bf16) @ W(NxK bf16)^T. Block 256thr/4 waves, tile
// 64m x 64n, wave = 16 rows x 4 n-frags. mfma_f32_16x16x32_bf16 layouts:
//   A/B frag: row(lane&15), k = (lane>>4)*8 + j
//   C/D frag: col(lane&15), row = (lane>>4)*4 + reg
// MODE 0: fp32 store, ldc=N. MODE 1 (in_proj): col<256 -> bf16 xcpre,
// col>=256 -> bf16 silu -> zact.
// ---------------------------------------------------------------------------
template<int N, int K, int MODE>
__global__ __launch_bounds__(256) void mgemm(const short* __restrict__ A,
                                             const short* __restrict__ W,
                                             float* __restrict__ C,
                                             short* __restrict__ xcpre,
                                             short* __restrict__ zact) {
  const int m_base = blockIdx.x * 64;
  const int n_base = blockIdx.y * 64;
  const int wave = threadIdx.x >> 6;
  const int lane = threadIdx.x & 63;
  const int r16  = lane & 15;
  const int quad = lane >> 4;
  f32x4 acc[4] = {};
  const short* Ap = A + (size_t)(m_base + wave * 16 + r16) * K + quad * 8;
  const short* Wp = W + (size_t)(n_base + r16) * K + quad * 8;
#pragma unroll
  for (int k0 = 0; k0 < K; k0 += 32) {
    bf16x8 a = *(const bf16x8*)(Ap + k0);
#pragma unroll
    for (int j = 0; j < 4; ++j) {
      bf16x8 b = *(const bf16x8*)(Wp + (size_t)j * 16 * K + k0);
      acc[j] = __builtin_amdgcn_mfma_f32_16x16x32_bf16(a, b, acc[j], 0, 0, 0);
    }
  }
#pragma unroll
  for (int j = 0; j < 4; ++j) {
    const int col = n_base + j * 16 + r16;
#pragma unroll
    for (int r = 0; r < 4; ++r) {
      const int row = m_base + wave * 16 + quad * 4 + r;
      if (MODE == 0) {
        C[(size_t)row * N + col] = acc[j][r];
      } else {
        if (col < 256) {
          xcpre[(size_t)row * 256 + col] = f2s(acc[j][r]);
        } else {
          float v = acc[j][r];
          zact[(size_t)row * 256 + (col - 256)] = f2s(v / (1.f + __expf(-v)));
        }
      }
    }
  }
}

// ---------------------------------------------------------------------------
// conv_silu2: depthwise causal conv (width 4) + bias + silu. Block = (b,
// 64-d tile), 256 thr = 64 d-lanes x 4 t-groups of 64. Each thread runs its
// t-range serially (coalesced 128B/wave input reads, 3-tap history in regs).
// Emits xcb (b,t,d) for the x_proj GEMM and, via LDS transpose, xcT (b,d,t)
// with 1KB-coalesced b128 stores.
// ---------------------------------------------------------------------------
__global__ __launch_bounds__(256) void conv_silu2(const short* __restrict__ xcpre,
                                                  const float* __restrict__ cw,
                                                  const float* __restrict__ cb,
                                                  short* __restrict__ xcb,
                                                  short* __restrict__ xcT) {
  const int b  = blockIdx.x >> 2;
  const int dt = (blockIdx.x & 3) * 64;
  const int tg = threadIdx.x >> 6;
  const int dl = threadIdx.x & 63;
  const int d  = dt + dl;
  const int t0 = tg * 64;
  __shared__ short L[64][264];                 // [d][t] bf16, stride 264 (16B-aligned)
  const float w0 = cw[d * 4], w1 = cw[d * 4 + 1], w2 = cw[d * 4 + 2], w3 = cw[d * 4 + 3];
  const float bias = cb[d];
  const size_t base = (size_t)b * 65536 + d;   // xcpre[(b,t,d)] = base + t*256
  float p0 = (t0 >= 3) ? s2f(xcpre[base + (size_t)(t0 - 3) * 256]) : 0.f;
  float p1 = (t0 >= 2) ? s2f(xcpre[base + (size_t)(t0 - 2) * 256]) : 0.f;
  float p2 = (t0 >= 1) ? s2f(xcpre[base + (size_t)(t0 - 1) * 256]) : 0.f;
  for (int t = t0; t < t0 + 64; ++t) {
    float cur = s2f(xcpre[base + (size_t)t * 256]);
    float acc = bias + p0 * w0 + p1 * w1 + p2 * w2 + cur * w3;
    short s = f2s(acc / (1.f + __expf(-acc)));
    xcb[base + (size_t)t * 256] = s;           // coalesced per t
    L[dl][t] = s;
    p0 = p1; p1 = p2; p2 = cur;
  }
  __syncthreads();
  // transpose write-out: per round, wave covers 2 full d-rows -> 1KB contig
#pragma unroll
  for (int r8 = 0; r8 < 8; ++r8) {
    const int dw = r8 * 8 + (threadIdx.x >> 5);
    const int tc = threadIdx.x & 31;
    bf16x8 v = *(const bf16x8*)(&L[dw][tc * 8]);
    *(bf16x8*)(xcT + ((size_t)b * 256 + dt + dw) * 256 + tc * 8) = v;
  }
}

// ---------------------------------------------------------------------------
// repack: delta = softplus(dt . dt_proj_w[d] + b[d]) and z-transpose.
// Same block/tile structure as conv_silu2; emits dT,zT in (b,d,t) bf16.
// ---------------------------------------------------------------------------
__global__ __launch_bounds__(256) void repack(const float* __restrict__ xdbl,
                                              const short* __restrict__ zact,
                                              const float* __restrict__ dtw,
                                              const float* __restrict__ dtb,
                                              short* __restrict__ dT,
                                              short* __restrict__ zT) {
  const int b  = blockIdx.x >> 2;
  const int dt = (blockIdx.x & 3) * 64;
  const int tg = threadIdx.x >> 6;
  const int dl = threadIdx.x & 63;
  const int d  = dt + dl;
  const int t0 = tg * 64;
  __shared__ short Ld[64][264], Lz[64][264];   // 2 x 33,792 B
  float wd[8];
#pragma unroll
  for (int j = 0; j < 8; ++j) wd[j] = dtw[d * 8 + j];
  const float bd = dtb[d];
  for (int t = t0; t < t0 + 64; ++t) {
    const float* r = xdbl + (size_t)(b * 256 + t) * 64;
    float acc = bd;
#pragma unroll
    for (int j = 0; j < 8; ++j) acc += r[j] * wd[j];
    const float delta = (acc > 20.f) ? acc : __logf(1.f + __expf(acc));
    Ld[dl][t] = f2s(delta);
    Lz[dl][t] = zact[(size_t)b * 65536 + (size_t)t * 256 + d];
  }
  __syncthreads();
#pragma unroll
  for (int r8 = 0; r8 < 8; ++r8) {
    const int dw = r8 * 8 + (threadIdx.x >> 5);
    const int tc = threadIdx.x & 31;
    const size_t o = ((size_t)b * 256 + dt + dw) * 256 + tc * 8;
    *(bf16x8*)(dT + o) = *(const bf16x8*)(&Ld[dw][tc * 8]);
    *(bf16x8*)(zT + o) = *(const bf16x8*)(&Lz[dw][tc * 8]);
  }
}

// ---------------------------------------------------------------------------
// scan6 (R1 form, 61.7us): state-parallel selective scan, register-pipelined.
// Block = (b, group of 32 d), 128 thr = 32 d x 4 lanes; lane owns 4 of 16
// states, serial T=256. S (B/C fp32, LDS) chunk loads named-double-buffered;
// u/delta/z chunk dbuf; zT load exec-masked q==0; exp2 with log2e in A.
// ---------------------------------------------------------------------------
#define SC6_PREFETCH(BUF, CH) do {                                           \
    _Pragma("unroll")                                                        \
    for (int j_ = 0; j_ < 8; ++j_) {                                         \
      SBr[BUF][j_] = *(const f32x4*)(&S[(CH) * 8 + j_][q * 4]);              \
      SCr[BUF][j_] = *(const f32x4*)(&S[(CH) * 8 + j_][16 + q * 4]);         \
    }                                                                        \
    uu[BUF] = *(const bf16x8*)(xcT + tb + (CH) * 8);                         \
    dd[BUF] = *(const bf16x8*)(dT + tb + (CH) * 8);                          \
    if (q == 0) zz[BUF] = *(const bf16x8*)(zT + tb + (CH) * 8);              \
  } while (0)

#define SC6_COMPUTE(BUF, CH) do {                                            \
    _Pragma("unroll")                                                        \
    for (int tt_ = 0; tt_ < 8; ++tt_) {                                      \
      const int t_ = (CH) * 8 + tt_;                                         \
      const float delta_ = s2f(dd[BUF][tt_]);                                \
      const float u_ = s2f(uu[BUF][tt_]);                                    \
      const float du_ = delta_ * u_;                                         \
      const f32x4 Bq_ = SBr[BUF][tt_];                                       \
      const f32x4 Cq_ = SCr[BUF][tt_];                                       \
      float yt_ = 0.f;                                                       \
      _Pragma("unroll")                                                      \
      for (int n_ = 0; n_ < 4; ++n_) {                                       \
        const float dA_ = __builtin_amdgcn_exp2f(delta_ * A2[n_]);           \
        h[n_] = dA_ * h[n_] + du_ * Bq_[n_];                                 \
        yt_ += h[n_] * Cq_[n_];                                              \
      }                                                                      \
      yt_ += __shfl_xor(yt_, 1);                                             \
      yt_ += __shfl_xor(yt_, 2);                                             \
      if (q == 0)                                                            \
        yb[(rb + t_) * 256 + d] = f2s((yt_ + u_ * Dv) * s2f(zz[BUF][tt_]));  \
    }                                                                        \
  } while (0)

__global__ __launch_bounds__(128, 2) void scan6(const float* __restrict__ xdbl,
                                                const short* __restrict__ xcT,
                                                const short* __restrict__ dT,
                                                const short* __restrict__ zT,
                                                const float* __restrict__ alog,
                                                const float* __restrict__ Dp,
                                                short* __restrict__ yb) {
  const int g = blockIdx.x & 7;
  const int b = blockIdx.x >> 3;
  const int q = threadIdx.x & 3;
  const int d = g * 32 + (threadIdx.x >> 2);
  const size_t rb = (size_t)b * 256;
  __shared__ float S[256][32];                // B(16)|C(16) fp32 per t, 32 KB
  for (int i = threadIdx.x; i < 2048; i += 128) {
    int row = i >> 3, c4 = i & 7;
    f32x4 v = *(const f32x4*)(xdbl + (rb + row) * 64 + 8 + c4 * 4);
    *(f32x4*)(&S[row][c4 * 4]) = v;
  }
  float A2[4];
#pragma unroll
  for (int n = 0; n < 4; ++n)
    A2[n] = -__expf(alog[d * 16 + q * 4 + n]) * 1.44269504089f;
  const float Dv = Dp[d];
  float h[4] = {0.f, 0.f, 0.f, 0.f};
  const size_t tb = ((size_t)b * 256 + d) * 256;   // t-row base (b,d,t)
  f32x4 SBr[2][8], SCr[2][8];
  bf16x8 uu[2], dd[2];
  bf16x8 zz[2] = {};
  // global chunk-0 loads can start before the LDS fill is visible
  uu[0] = *(const bf16x8*)(xcT + tb);
  dd[0] = *(const bf16x8*)(dT + tb);
  if (q == 0) zz[0] = *(const bf16x8*)(zT + tb);
  __syncthreads();
#pragma unroll
  for (int j_ = 0; j_ < 8; ++j_) {
    SBr[0][j_] = *(const f32x4*)(&S[j_][q * 4]);
    SCr[0][j_] = *(const f32x4*)(&S[j_][16 + q * 4]);
  }
  for (int c = 0; c < 32; c += 2) {
    SC6_PREFETCH(1, c + 1);
    SC6_COMPUTE(0, c);
    if (c + 2 < 32) SC6_PREFETCH(0, c + 2);
    SC6_COMPUTE(1, c + 1);
  }
}

// ---------------------------------------------------------------------------
// od_k: fused out_proj + strided down-conv + bias + LayerNorm.
//   pre[b,to,co] = sum_{k=0..2} yb[b, 2to+k-1, :] . G_k[co, :]  + db[co]
//   out = LN(pre) over co (128), eps 1e-5.
// Grid 256 blocks x 256 thr (4 waves x 16 m-rows); m = b*128+to. K=768 via
// 3 row-shifted K=256 segments (t' = 2to+k-1, clamped load + zero mask at
// boundaries). G is 196KB -> L2-resident. LN fused: each wave holds full
// 128-col rows; 16-lane shfl_xor reductions within quad groups.
// ---------------------------------------------------------------------------
__global__ __launch_bounds__(256) void od_k(const short* __restrict__ yb,
                                            const short* __restrict__ G,
                                            const float* __restrict__ db,
                                            const float* __restrict__ lng,
                                            const float* __restrict__ lnb,
                                            float* __restrict__ out) {
  const int wave = threadIdx.x >> 6;
  const int lane = threadIdx.x & 63;
  const int r16  = lane & 15;
  const int quad = lane >> 4;
  const int m_base = blockIdx.x * 64 + wave * 16;
  // A-load row for this lane
  const int ma = m_base + r16;
  const int ba = ma >> 7, toa = ma & 127;
  f32x4 acc[8] = {};
  const bf16x8 az = {};
#pragma unroll
  for (int k = 0; k < 3; ++k) {
    const int tp = 2 * toa + k - 1;
    const bool valid = (tp >= 0) && (tp < 256);
    const int tpc = tp < 0 ? 0 : (tp > 255 ? 255 : tp);
    const short* Ap = yb + (size_t)(ba * 256 + tpc) * 256 + quad * 8;
    const short* Gp = G + (size_t)(k * 128 + r16) * 256 + quad * 8;
#pragma unroll
    for (int k0 = 0; k0 < 256; k0 += 32) {
      bf16x8 a = *(const bf16x8*)(Ap + k0);
      a = valid ? a : az;
#pragma unroll
      for (int j = 0; j < 8; ++j) {
        bf16x8 g = *(const bf16x8*)(Gp + (size_t)j * 16 * 256 + k0);
        acc[j] = __builtin_amdgcn_mfma_f32_16x16x32_bf16(a, g, acc[j], 0, 0, 0);
      }
    }
  }
  // epilogue: bias + LayerNorm. lane holds rows {quad*4+r}, cols {j*16+r16}.
  float dbv[8], g8[8], be8[8];
#pragma unroll
  for (int j = 0; j < 8; ++j) {
    const int col = j * 16 + r16;
    dbv[j] = db[col]; g8[j] = lng[col]; be8[j] = lnb[col];
  }
#pragma unroll
  for (int r = 0; r < 4; ++r) {
    float v[8];
    float s = 0.f;
#pragma unroll
    for (int j = 0; j < 8; ++j) { v[j] = acc[j][r] + dbv[j]; s += v[j]; }
    s += __shfl_xor(s, 1); s += __shfl_xor(s, 2);
    s += __shfl_xor(s, 4); s += __shfl_xor(s, 8);
    const float mu = s * (1.0f / 128.0f);
    float vs = 0.f;
#pragma unroll
    for (int j = 0; j < 8; ++j) { const float dd = v[j] - mu; vs += dd * dd; }
    vs += __shfl_xor(vs, 1); vs += __shfl_xor(vs, 2);
    vs += __shfl_xor(vs, 4); vs += __shfl_xor(vs, 8);
    const float rstd = rsqrtf(vs * (1.0f / 128.0f) + 1e-5f);
    const int rowm = m_base + quad * 4 + r;
#pragma unroll
    for (int j = 0; j < 8; ++j) {
      out[(size_t)rowm * 128 + j * 16 + r16] = (v[j] - mu) * rstd * g8[j] + be8[j];
    }
  }
}

// ---------------------------------------------------------------------------
// Workspace layout (bytes), peak 92,471,296 == proven-safe bound:
//   [0,16M)      xcpre bf16 (in_proj->conv) -> yb bf16 (scan->od_k)
//   [16M,32M)    xcT bf16 (conv->scan)
//   [32M,48M)    zact bf16 (in_proj->repack)
//   [48M,64M)    xcb bf16 (conv->xproj) -> dT bf16 (repack->scan)
//   [64M,72M)    xdbl fp32 (xproj->scan)
//   [72M,88M)    xb bf16 8.4MB (cvt->in_proj) -> zT bf16 (repack->scan)
//   [88M,88.2M)  ipwb bf16 131,072B (prep->in_proj) -> G bf16 196,608B
//                (g_prep->od_k; g_prep launched AFTER in_proj consumed ipwb;
//                 region ends exactly at 92,471,296)
// d_out staging: wxb (32KB bf16) at out0 base (od_k writes out0 LAST);
// out1 written once by cvt_x.
// ---------------------------------------------------------------------------
static const size_t O_XCPRE = 0;            // also yb
static const size_t O_XCT   = 16777216;
static const size_t O_ZACT  = 33554432;
static const size_t O_XCB   = 50331648;     // also dT
static const size_t O_XDBL  = 67108864;
static const size_t O_XB    = 75497472;     // also zT (16,777,216 B)
static const size_t O_IPWB  = 92274688;     // 131,072 B; then G 196,608 B

extern "C" void kernel_launch(void* const* d_in, const int* in_sizes, int n_in,
                              void* d_out, int out_size, void* d_ws, size_t ws_size,
                              hipStream_t stream) {
  const float* x    = (const float*)d_in[0];
  const float* ipw  = (const float*)d_in[1];
  const float* cw   = (const float*)d_in[2];
  const float* cb   = (const float*)d_in[3];
  const float* xpw  = (const float*)d_in[4];
  const float* dtw  = (const float*)d_in[5];
  const float* dtb  = (const float*)d_in[6];
  const float* alog = (const float*)d_in[7];
  const float* Dp   = (const float*)d_in[8];
  const float* opw  = (const float*)d_in[9];
  const float* dw   = (const float*)d_in[10];
  const float* db   = (const float*)d_in[11];
  const float* lng  = (const float*)d_in[12];
  const float* lnb  = (const float*)d_in[13];

  char*  ws     = (char*)d_ws;
  short* xcpre  = (short*)(ws + O_XCPRE);
  short* yb     = (short*)(ws + O_XCPRE);  // alias (xcpre dead after conv)
  short* xcT    = (short*)(ws + O_XCT);
  short* zact   = (short*)(ws + O_ZACT);
  short* xcb    = (short*)(ws + O_XCB);
  short* dT     = (short*)(ws + O_XCB);    // alias (xcb dead after xproj)
  float* xdbl   = (float*)(ws + O_XDBL);
  short* xb     = (short*)(ws + O_XB);
  short* zT     = (short*)(ws + O_XB);     // alias (xb dead after in_proj)
  short* ipwb   = (short*)(ws + O_IPWB);
  short* G      = (short*)(ws + O_IPWB);   // alias (ipwb dead after in_proj)
  float* out    = (float*)d_out;
  short* wxb    = (short*)out;             // out0 staging; od_k writes last
  float* out1   = out + 2097152;

  // 0. x -> bf16 + x_skip passthrough; weight prep
  cvt_x<<<4096, 256, 0, stream>>>(x, xb, out1);
  prep_w<<<320, 256, 0, stream>>>(ipw, xpw, ipwb, wxb);
  // 1. in_proj MFMA (32768x512, K=128) -> bf16 xcpre + bf16 silu(z)
  mgemm<512, 128, 1><<<dim3(512, 8), 256, 0, stream>>>(
      xb, ipwb, nullptr, xcpre, zact);
  // 2. fused tail weight G_k = dwn_k @ opw (overwrites ipwb -- consumed)
  g_prep<<<384, 256, 0, stream>>>(dw, opw, G);
  // 3. depthwise causal conv + silu -> xcb (b,t,d) + xcT (b,d,t)
  conv_silu2<<<512, 256, 0, stream>>>(xcpre, cw, cb, xcb, xcT);
  // 4. x_dbl MFMA: xcb @ wxb^T (32768x64, K=256) -> fp32 xdbl
  mgemm<64, 256, 0><<<dim3(512, 1), 256, 0, stream>>>(
      xcb, wxb, xdbl, nullptr, nullptr);
  // 5. delta + z transpose -> dT, zT (b,d,t)
  repack<<<512, 256, 0, stream>>>(xdbl, zact, dtw, dtb, dT, zT);
  // 6. state-parallel scan -> yb bf16
  scan6<<<1024, 128, 0, stream>>>(xdbl, xcT, dT, zT, alog, Dp, yb);
  // 7. fused out_proj + down-conv + bias + LayerNorm -> output 0
  od_k<<<256, 256, 0, stream>>>(yb, G, db, lng, lnb, out);
}

// Round 4
// 263.375 us; speedup vs baseline: 1.3251x; 1.1347x over previous
//
#include <hip/hip_runtime.h>
#include <hip/hip_bf16.h>

// Problem dims (fixed by reference)
//   B=128, T=256, D_MODEL=128, D_INNER=256, D_STATE=16, D_CONV=4, DT_RANK=8
// I/O dtype: float32. MFMA bf16 for in_proj/x_proj/fused-tail. R15:
//  - NEW mid_k: conv_silu2 + x_proj GEMM + repack fused into one kernel per
//    (b, 64-t quarter). Kills xcb (33.5MB round-trip), xdbl (8.4MB -> dense
//    4MB SBC), one transpose pass, and 2 launches. conv results flow
//    regs->xcT directly; x_proj runs as in-LDS MFMA (M=64,N=64,K=256);
//    delta from LDS-broadcast dt rows -> dT direct.
//  - scan6 unchanged (R1 form, 62us) except S-fill reads dense SBC (b,t,32).
//  - od_k (R14): out_proj+down-conv+bias+LN as one K=768 MFMA GEMM.
// Outputs: h (128,128,128) then x_skip (128,256,128), fp32, concatenated.

typedef __attribute__((ext_vector_type(8))) short bf16x8;
typedef __attribute__((ext_vector_type(4))) short bf16x4;
typedef __attribute__((ext_vector_type(4))) float f32x4;
using bf16 = __hip_bfloat16;

static __device__ __forceinline__ short f2s(float v) {
  union { bf16 b; short s; } u; u.b = (bf16)v; return u.s;
}
static __device__ __forceinline__ float s2f(short s) {
  union { short s; bf16 b; } u; u.s = s; return (float)u.b;
}

// ---------------------------------------------------------------------------
// cvt_x: x fp32 -> bf16 xb AND x_skip passthrough (out1), 4 elems/thread.
// ---------------------------------------------------------------------------
__global__ __launch_bounds__(256) void cvt_x(const float* __restrict__ x,
                                             short* __restrict__ xb,
                                             float* __restrict__ out1) {
  int i = (blockIdx.x * 256 + threadIdx.x) * 4;
  f32x4 v = *(const f32x4*)(x + i);
  bf16x4 o;
  o[0] = f2s(v[0]); o[1] = f2s(v[1]); o[2] = f2s(v[2]); o[3] = f2s(v[3]);
  *(bf16x4*)(xb + i) = o;
  *(f32x4*)(out1 + i) = v;
}

// ---------------------------------------------------------------------------
// Weight prep: ipw(512x128)->bf16 (ws), x_proj_w -> wxb (64x256 bf16, rows
// 40..63 zero; staged in out0 -- safe: od_k writes out0 LAST, after wxb use).
// ---------------------------------------------------------------------------
__global__ __launch_bounds__(256) void prep_w(const float* __restrict__ ipw,
                                              const float* __restrict__ xpw,
                                              short* __restrict__ ipwb,
                                              short* __restrict__ wxb) {
  int idx = blockIdx.x * 256 + threadIdx.x;   // 0 .. 81919
  if (idx < 65536) {
    ipwb[idx] = f2s(ipw[idx]);
  } else {
    int j = idx - 65536;          // n*256 + k
    int n = j >> 8;
    wxb[j] = (n < 40) ? f2s(xpw[j]) : (short)0;
  }
}

// ---------------------------------------------------------------------------
// g_prep: fused tail weight G_k[co,e] = sum_dm dwn[co,dm,k] * opw[dm,e].
// Block = (k*128+co), 256 thr = e. fp32 dot, bf16 store. 12.6 MFLOP, tiny.
// G lives in the ipwb tail region (ipwb dead after in_proj; launched after).
// ---------------------------------------------------------------------------
__global__ __launch_bounds__(256) void g_prep(const float* __restrict__ dwn,
                                              const float* __restrict__ opw,
                                              short* __restrict__ G) {
  const int k  = blockIdx.x >> 7;
  const int co = blockIdx.x & 127;
  const int e  = threadIdx.x;
  float acc = 0.f;
  for (int dm = 0; dm < 128; ++dm) {
    acc += dwn[(co * 128 + dm) * 3 + k] * opw[dm * 256 + e];
  }
  G[(size_t)(k * 128 + co) * 256 + e] = f2s(acc);
}

// ---------------------------------------------------------------------------
// MFMA GEMM: C = A(MxK bf16) @ W(NxK bf16)^T. Block 256thr/4 waves, tile
// 64m x 64n, wave = 16 rows x 4 n-frags. mfma_f32_16x16x32_bf16 layouts:
//   A/B frag: row(lane&15), k = (lane>>4)*8 + j
//   C/D frag: col(lane&15), row = (lane>>4)*4 + reg
// MODE 1 (in_proj): col<256 -> bf16 xcpre, col>=256 -> bf16 silu -> zact.
// ---------------------------------------------------------------------------
template<int N, int K, int MODE>
__global__ __launch_bounds__(256) void mgemm(const short* __restrict__ A,
                                             const short* __restrict__ W,
                                             float* __restrict__ C,
                                             short* __restrict__ xcpre,
                                             short* __restrict__ zact) {
  const int m_base = blockIdx.x * 64;
  const int n_base = blockIdx.y * 64;
  const int wave = threadIdx.x >> 6;
  const int lane = threadIdx.x & 63;
  const int r16  = lane & 15;
  const int quad = lane >> 4;
  f32x4 acc[4] = {};
  const short* Ap = A + (size_t)(m_base + wave * 16 + r16) * K + quad * 8;
  const short* Wp = W + (size_t)(n_base + r16) * K + quad * 8;
#pragma unroll
  for (int k0 = 0; k0 < K; k0 += 32) {
    bf16x8 a = *(const bf16x8*)(Ap + k0);
#pragma unroll
    for (int j = 0; j < 4; ++j) {
      bf16x8 b = *(const bf16x8*)(Wp + (size_t)j * 16 * K + k0);
      acc[j] = __builtin_amdgcn_mfma_f32_16x16x32_bf16(a, b, acc[j], 0, 0, 0);
    }
  }
#pragma unroll
  for (int j = 0; j < 4; ++j) {
    const int col = n_base + j * 16 + r16;
#pragma unroll
    for (int r = 0; r < 4; ++r) {
      const int row = m_base + wave * 16 + quad * 4 + r;
      if (MODE == 0) {
        C[(size_t)row * N + col] = acc[j][r];
      } else {
        if (col < 256) {
          xcpre[(size_t)row * 256 + col] = f2s(acc[j][r]);
        } else {
          float v = acc[j][r];
          zact[(size_t)row * 256 + (col - 256)] = f2s(v / (1.f + __expf(-v)));
        }
      }
    }
  }
}

// ---------------------------------------------------------------------------
// mid_k: fused depthwise conv+silu + x_proj MFMA + delta(softplus) + z/u
// transposes. Block = (b, 64-t quarter); 512 blocks x 256 thr.
//  phase 1: conv+silu per (d, 16t) thread (3-tap history from xcpre global);
//           xc -> LDS[t][d] + regs -> xcT (b,d,t); z -> regs -> zT (b,d,t).
//  phase 2: x_proj MFMA M=64(t) N=64 K=256(d), A from LDS, W=wxb (L2-hot).
//           dt cols (0..7) -> DTL LDS; B/C cols (8..39) -> SBC (b,t,32) fp32.
//  phase 3: delta = softplus(dt . dtw[d] + dtb[d]) -> dT (b,d,t).
// LDS 35.8KB -> 2 blocks/CU at grid 512.
// ---------------------------------------------------------------------------
__global__ __launch_bounds__(256) void mid_k(const short* __restrict__ xcpre,
                                             const float* __restrict__ cw,
                                             const float* __restrict__ cb,
                                             const short* __restrict__ wxb,
                                             const short* __restrict__ zact,
                                             const float* __restrict__ dtw,
                                             const float* __restrict__ dtb,
                                             short* __restrict__ xcT,
                                             short* __restrict__ dT,
                                             short* __restrict__ zT,
                                             float* __restrict__ SBC) {
  const int b  = blockIdx.x >> 2;
  const int t0 = (blockIdx.x & 3) * 64;       // t-quarter base
  const int tg = threadIdx.x >> 6;            // 4 groups of 16 t
  const int dl = threadIdx.x & 63;
  __shared__ short XC[64][264];               // [t-local][d] bf16, pad 8
  __shared__ float DTL[64][8];                // dt cols per t-local
  const int tA = t0 + tg * 16;                // absolute start t
  // ---- phase 1: conv+silu (+z gather), 4 d-tiles x 16 t per thread ----
#pragma unroll
  for (int dtile = 0; dtile < 4; ++dtile) {
    const int d = dtile * 64 + dl;
    const float w0 = cw[d * 4], w1 = cw[d * 4 + 1];
    const float w2 = cw[d * 4 + 2], w3 = cw[d * 4 + 3];
    const float bias = cb[d];
    const size_t base = (size_t)b * 65536 + d;  // (b,t,d) row base
    float p0 = (tA >= 3) ? s2f(xcpre[base + (size_t)(tA - 3) * 256]) : 0.f;
    float p1 = (tA >= 2) ? s2f(xcpre[base + (size_t)(tA - 2) * 256]) : 0.f;
    float p2 = (tA >= 1) ? s2f(xcpre[base + (size_t)(tA - 1) * 256]) : 0.f;
    bf16x8 xr0, xr1, zr0, zr1;
#pragma unroll
    for (int i = 0; i < 16; ++i) {
      const int t = tA + i;
      float cur = s2f(xcpre[base + (size_t)t * 256]);
      float acc = bias + p0 * w0 + p1 * w1 + p2 * w2 + cur * w3;
      short s = f2s(acc / (1.f + __expf(-acc)));
      XC[tg * 16 + i][d] = s;
      short z = zact[base + (size_t)t * 256];
      if (i < 8) { xr0[i] = s; zr0[i] = z; } else { xr1[i - 8] = s; zr1[i - 8] = z; }
      p0 = p1; p1 = p2; p2 = cur;
    }
    const size_t ob = ((size_t)b * 256 + d) * 256 + tA;
    *(bf16x8*)(xcT + ob)     = xr0;
    *(bf16x8*)(xcT + ob + 8) = xr1;
    *(bf16x8*)(zT + ob)      = zr0;
    *(bf16x8*)(zT + ob + 8)  = zr1;
  }
  __syncthreads();
  // ---- phase 2: x_proj MFMA (A = XC, W = wxb) ----
  {
    const int lane = threadIdx.x & 63;
    const int r16  = lane & 15;
    const int quad = lane >> 4;
    f32x4 acc[4] = {};
    const short* Wp = wxb + (size_t)r16 * 256 + quad * 8;
    const short* Xp = &XC[tg * 16 + r16][quad * 8];
#pragma unroll
    for (int k0 = 0; k0 < 256; k0 += 32) {
      bf16x8 a = *(const bf16x8*)(Xp + k0);
#pragma unroll
      for (int j = 0; j < 4; ++j) {
        bf16x8 bb = *(const bf16x8*)(Wp + (size_t)j * 16 * 256 + k0);
        acc[j] = __builtin_amdgcn_mfma_f32_16x16x32_bf16(a, bb, acc[j], 0, 0, 0);
      }
    }
    // scatter: cols<8 -> DTL (LDS); 8<=col<40 -> SBC (global, fp32)
#pragma unroll
    for (int j = 0; j < 3; ++j) {
      const int col = j * 16 + r16;
#pragma unroll
      for (int r = 0; r < 4; ++r) {
        const int tl = tg * 16 + quad * 4 + r;
        if (col < 8) {
          DTL[tl][col] = acc[j][r];
        } else if (col < 40) {
          SBC[((size_t)b * 256 + t0 + tl) * 32 + (col - 8)] = acc[j][r];
        }
      }
    }
  }
  __syncthreads();
  // ---- phase 3: delta = softplus(dt . dtw + dtb) -> dT ----
#pragma unroll
  for (int dtile = 0; dtile < 4; ++dtile) {
    const int d = dtile * 64 + dl;
    float wd[8];
#pragma unroll
    for (int j = 0; j < 8; ++j) wd[j] = dtw[d * 8 + j];
    const float bd = dtb[d];
    bf16x8 dr0, dr1;
#pragma unroll
    for (int i = 0; i < 16; ++i) {
      const float* r = &DTL[tg * 16 + i][0];
      float acc = bd;
#pragma unroll
      for (int j = 0; j < 8; ++j) acc += r[j] * wd[j];
      const float delta = (acc > 20.f) ? acc : __logf(1.f + __expf(acc));
      short s = f2s(delta);
      if (i < 8) dr0[i] = s; else dr1[i - 8] = s;
    }
    const size_t ob = ((size_t)b * 256 + d) * 256 + tA;
    *(bf16x8*)(dT + ob)     = dr0;
    *(bf16x8*)(dT + ob + 8) = dr1;
  }
}

// ---------------------------------------------------------------------------
// scan6 (R1 form, 62us): state-parallel selective scan, register-pipelined.
// Block = (b, group of 32 d), 128 thr = 32 d x 4 lanes; lane owns 4 of 16
// states, serial T=256. S (B/C fp32, LDS) chunk loads named-double-buffered;
// u/delta/z chunk dbuf; zT load exec-masked q==0; exp2 with log2e in A.
// S-fill now reads dense SBC (b,t,32) fp32 -- fully coalesced.
// ---------------------------------------------------------------------------
#define SC6_PREFETCH(BUF, CH) do {                                           \
    _Pragma("unroll")                                                        \
    for (int j_ = 0; j_ < 8; ++j_) {                                         \
      SBr[BUF][j_] = *(const f32x4*)(&S[(CH) * 8 + j_][q * 4]);              \
      SCr[BUF][j_] = *(const f32x4*)(&S[(CH) * 8 + j_][16 + q * 4]);         \
    }                                                                        \
    uu[BUF] = *(const bf16x8*)(xcT + tb + (CH) * 8);                         \
    dd[BUF] = *(const bf16x8*)(dT + tb + (CH) * 8);                          \
    if (q == 0) zz[BUF] = *(const bf16x8*)(zT + tb + (CH) * 8);              \
  } while (0)

#define SC6_COMPUTE(BUF, CH) do {                                            \
    _Pragma("unroll")                                                        \
    for (int tt_ = 0; tt_ < 8; ++tt_) {                                      \
      const int t_ = (CH) * 8 + tt_;                                         \
      const float delta_ = s2f(dd[BUF][tt_]);                                \
      const float u_ = s2f(uu[BUF][tt_]);                                    \
      const float du_ = delta_ * u_;                                         \
      const f32x4 Bq_ = SBr[BUF][tt_];                                       \
      const f32x4 Cq_ = SCr[BUF][tt_];                                       \
      float yt_ = 0.f;                                                       \
      _Pragma("unroll")                                                      \
      for (int n_ = 0; n_ < 4; ++n_) {                                       \
        const float dA_ = __builtin_amdgcn_exp2f(delta_ * A2[n_]);           \
        h[n_] = dA_ * h[n_] + du_ * Bq_[n_];                                 \
        yt_ += h[n_] * Cq_[n_];                                              \
      }                                                                      \
      yt_ += __shfl_xor(yt_, 1);                                             \
      yt_ += __shfl_xor(yt_, 2);                                             \
      if (q == 0)                                                            \
        yb[(rb + t_) * 256 + d] = f2s((yt_ + u_ * Dv) * s2f(zz[BUF][tt_]));  \
    }                                                                        \
  } while (0)

__global__ __launch_bounds__(128, 2) void scan6(const float* __restrict__ SBC,
                                                const short* __restrict__ xcT,
                                                const short* __restrict__ dT,
                                                const short* __restrict__ zT,
                                                const float* __restrict__ alog,
                                                const float* __restrict__ Dp,
                                                short* __restrict__ yb) {
  const int g = blockIdx.x & 7;
  const int b = blockIdx.x >> 3;
  const int q = threadIdx.x & 3;
  const int d = g * 32 + (threadIdx.x >> 2);
  const size_t rb = (size_t)b * 256;
  __shared__ float S[256][32];                // B(16)|C(16) fp32 per t, 32 KB
  for (int i = threadIdx.x; i < 2048; i += 128) {
    *(f32x4*)(&S[i >> 3][(i & 7) * 4]) =
        *(const f32x4*)(SBC + (size_t)b * 8192 + i * 4);
  }
  float A2[4];
#pragma unroll
  for (int n = 0; n < 4; ++n)
    A2[n] = -__expf(alog[d * 16 + q * 4 + n]) * 1.44269504089f;
  const float Dv = Dp[d];
  float h[4] = {0.f, 0.f, 0.f, 0.f};
  const size_t tb = ((size_t)b * 256 + d) * 256;   // t-row base (b,d,t)
  f32x4 SBr[2][8], SCr[2][8];
  bf16x8 uu[2], dd[2];
  bf16x8 zz[2] = {};
  // global chunk-0 loads can start before the LDS fill is visible
  uu[0] = *(const bf16x8*)(xcT + tb);
  dd[0] = *(const bf16x8*)(dT + tb);
  if (q == 0) zz[0] = *(const bf16x8*)(zT + tb);
  __syncthreads();
#pragma unroll
  for (int j_ = 0; j_ < 8; ++j_) {
    SBr[0][j_] = *(const f32x4*)(&S[j_][q * 4]);
    SCr[0][j_] = *(const f32x4*)(&S[j_][16 + q * 4]);
  }
  for (int c = 0; c < 32; c += 2) {
    SC6_PREFETCH(1, c + 1);
    SC6_COMPUTE(0, c);
    if (c + 2 < 32) SC6_PREFETCH(0, c + 2);
    SC6_COMPUTE(1, c + 1);
  }
}

// ---------------------------------------------------------------------------
// od_k: fused out_proj + strided down-conv + bias + LayerNorm.
//   pre[b,to,co] = sum_{k=0..2} yb[b, 2to+k-1, :] . G_k[co, :]  + db[co]
//   out = LN(pre) over co (128), eps 1e-5.
// Grid 256 blocks x 256 thr (4 waves x 16 m-rows); m = b*128+to. K=768 via
// 3 row-shifted K=256 segments. G is 196KB -> L2-resident. LN fused: 16-lane
// shfl_xor reductions.
// ---------------------------------------------------------------------------
__global__ __launch_bounds__(256) void od_k(const short* __restrict__ yb,
                                            const short* __restrict__ G,
                                            const float* __restrict__ db,
                                            const float* __restrict__ lng,
                                            const float* __restrict__ lnb,
                                            float* __restrict__ out) {
  const int wave = threadIdx.x >> 6;
  const int lane = threadIdx.x & 63;
  const int r16  = lane & 15;
  const int quad = lane >> 4;
  const int m_base = blockIdx.x * 64 + wave * 16;
  const int ma = m_base + r16;
  const int ba = ma >> 7, toa = ma & 127;
  f32x4 acc[8] = {};
  const bf16x8 az = {};
#pragma unroll
  for (int k = 0; k < 3; ++k) {
    const int tp = 2 * toa + k - 1;
    const bool valid = (tp >= 0) && (tp < 256);
    const int tpc = tp < 0 ? 0 : (tp > 255 ? 255 : tp);
    const short* Ap = yb + (size_t)(ba * 256 + tpc) * 256 + quad * 8;
    const short* Gp = G + (size_t)(k * 128 + r16) * 256 + quad * 8;
#pragma unroll
    for (int k0 = 0; k0 < 256; k0 += 32) {
      bf16x8 a = *(const bf16x8*)(Ap + k0);
      a = valid ? a : az;
#pragma unroll
      for (int j = 0; j < 8; ++j) {
        bf16x8 g = *(const bf16x8*)(Gp + (size_t)j * 16 * 256 + k0);
        acc[j] = __builtin_amdgcn_mfma_f32_16x16x32_bf16(a, g, acc[j], 0, 0, 0);
      }
    }
  }
  float dbv[8], g8[8], be8[8];
#pragma unroll
  for (int j = 0; j < 8; ++j) {
    const int col = j * 16 + r16;
    dbv[j] = db[col]; g8[j] = lng[col]; be8[j] = lnb[col];
  }
#pragma unroll
  for (int r = 0; r < 4; ++r) {
    float v[8];
    float s = 0.f;
#pragma unroll
    for (int j = 0; j < 8; ++j) { v[j] = acc[j][r] + dbv[j]; s += v[j]; }
    s += __shfl_xor(s, 1); s += __shfl_xor(s, 2);
    s += __shfl_xor(s, 4); s += __shfl_xor(s, 8);
    const float mu = s * (1.0f / 128.0f);
    float vs = 0.f;
#pragma unroll
    for (int j = 0; j < 8; ++j) { const float dd = v[j] - mu; vs += dd * dd; }
    vs += __shfl_xor(vs, 1); vs += __shfl_xor(vs, 2);
    vs += __shfl_xor(vs, 4); vs += __shfl_xor(vs, 8);
    const float rstd = rsqrtf(vs * (1.0f / 128.0f) + 1e-5f);
    const int rowm = m_base + quad * 4 + r;
#pragma unroll
    for (int j = 0; j < 8; ++j) {
      out[(size_t)rowm * 128 + j * 16 + r16] = (v[j] - mu) * rstd * g8[j] + be8[j];
    }
  }
}

// ---------------------------------------------------------------------------
// Workspace layout (bytes), peak 92,471,296 == proven-safe bound:
//   [0,16M)      xcpre bf16 (in_proj->mid_k) -> yb bf16 (scan->od_k)
//   [16M,32M)    xcT bf16 (mid_k->scan)
//   [32M,48M)    zact bf16 (in_proj->mid_k)
//   [48M,64M)    dT bf16 (mid_k->scan)
//   [64M,68.2M)  SBC fp32 4MB (mid_k->scan)
//   [72M,88M)    xb bf16 8.4MB (cvt->in_proj) -> zT bf16 (mid_k->scan)
//   [88M,88.2M)  ipwb bf16 131,072B (prep->in_proj) -> G bf16 196,608B
//                (g_prep->od_k; launched AFTER in_proj consumed ipwb;
//                 region ends exactly at 92,471,296)
// d_out staging: wxb (32KB bf16) at out0 base (od_k writes out0 LAST);
// out1 written once by cvt_x.
// ---------------------------------------------------------------------------
static const size_t O_XCPRE = 0;            // also yb
static const size_t O_XCT   = 16777216;
static const size_t O_ZACT  = 33554432;
static const size_t O_DT    = 50331648;
static const size_t O_SBC   = 67108864;
static const size_t O_XB    = 75497472;     // also zT
static const size_t O_IPWB  = 92274688;     // 131,072 B; then G 196,608 B

extern "C" void kernel_launch(void* const* d_in, const int* in_sizes, int n_in,
                              void* d_out, int out_size, void* d_ws, size_t ws_size,
                              hipStream_t stream) {
  const float* x    = (const float*)d_in[0];
  const float* ipw  = (const float*)d_in[1];
  const float* cw   = (const float*)d_in[2];
  const float* cb   = (const float*)d_in[3];
  const float* xpw  = (const float*)d_in[4];
  const float* dtw  = (const float*)d_in[5];
  const float* dtb  = (const float*)d_in[6];
  const float* alog = (const float*)d_in[7];
  const float* Dp   = (const float*)d_in[8];
  const float* opw  = (const float*)d_in[9];
  const float* dw   = (const float*)d_in[10];
  const float* db   = (const float*)d_in[11];
  const float* lng  = (const float*)d_in[12];
  const float* lnb  = (const float*)d_in[13];

  char*  ws     = (char*)d_ws;
  short* xcpre  = (short*)(ws + O_XCPRE);
  short* yb     = (short*)(ws + O_XCPRE);  // alias (xcpre dead after mid_k)
  short* xcT    = (short*)(ws + O_XCT);
  short* zact   = (short*)(ws + O_ZACT);
  short* dT     = (short*)(ws + O_DT);
  float* SBC    = (float*)(ws + O_SBC);
  short* xb     = (short*)(ws + O_XB);
  short* zT     = (short*)(ws + O_XB);     // alias (xb dead after in_proj)
  short* ipwb   = (short*)(ws + O_IPWB);
  short* G      = (short*)(ws + O_IPWB);   // alias (ipwb dead after in_proj)
  float* out    = (float*)d_out;
  short* wxb    = (short*)out;             // out0 staging; od_k writes last
  float* out1   = out + 2097152;

  // 0. x -> bf16 + x_skip passthrough; weight prep
  cvt_x<<<4096, 256, 0, stream>>>(x, xb, out1);
  prep_w<<<320, 256, 0, stream>>>(ipw, xpw, ipwb, wxb);
  // 1. in_proj MFMA (32768x512, K=128) -> bf16 xcpre + bf16 silu(z)
  mgemm<512, 128, 1><<<dim3(512, 8), 256, 0, stream>>>(
      xb, ipwb, nullptr, xcpre, zact);
  // 2. fused tail weight G_k = dwn_k @ opw (overwrites ipwb -- consumed)
  g_prep<<<384, 256, 0, stream>>>(dw, opw, G);
  // 3. fused conv+silu + x_proj + delta/transposes
  mid_k<<<512, 256, 0, stream>>>(xcpre, cw, cb, wxb, zact, dtw, dtb,
                                 xcT, dT, zT, SBC);
  // 4. state-parallel scan -> yb bf16
  scan6<<<1024, 128, 0, stream>>>(SBC, xcT, dT, zT, alog, Dp, yb);
  // 5. fused out_proj + down-conv + bias + LayerNorm -> output 0
  od_k<<<256, 256, 0, stream>>>(yb, G, db, lng, lnb, out);
}

// Round 5
// 255.973 us; speedup vs baseline: 1.3635x; 1.0289x over previous
//
#include <hip/hip_runtime.h>
#include <hip/hip_bf16.h>

// Problem dims (fixed by reference)
//   B=128, T=256, D_MODEL=128, D_INNER=256, D_STATE=16, D_CONV=4, DT_RANK=8
// I/O dtype: float32. MFMA bf16 for in_proj/x_proj/fused-tail. R16:
//  - R15 post-mortem: mid_k was 81us, latency-bound (VALUBusy 14%, occ 21.7%)
//    from 128 scalar stride-512B global loads/thread (xcpre+zact) and a
//    2-blocks/CU grid cap.
//  - inproj_k now writes BOTH outputs transposed (b,d,t) via a 9KB LDS
//    transpose tile: xcpreT and zT. Deletes zact entirely (33.5MB traffic)
//    and makes mid_k's conv input vector-loadable along t.
//  - mid_k v2: per (b,32-t) block (1024 blocks -> 4 blocks/CU, 50% occ cap);
//    conv reads bf16x8 vectors from xcpreT (9 vec loads/thread vs 128
//    scalar); x_proj MFMA M=32 from XC LDS ([32][264] pad keeps A-reads
//    bank-uniform); delta from DTL f32x4 broadcasts.
//  - scan6 (R1 form) and od_k (R14) unchanged.
// Outputs: h (128,128,128) then x_skip (128,256,128), fp32, concatenated.

typedef __attribute__((ext_vector_type(8))) short bf16x8;
typedef __attribute__((ext_vector_type(4))) short bf16x4;
typedef __attribute__((ext_vector_type(4))) float f32x4;
using bf16 = __hip_bfloat16;

static __device__ __forceinline__ short f2s(float v) {
  union { bf16 b; short s; } u; u.b = (bf16)v; return u.s;
}
static __device__ __forceinline__ float s2f(short s) {
  union { short s; bf16 b; } u; u.s = s; return (float)u.b;
}

// ---------------------------------------------------------------------------
// cvt_x: x fp32 -> bf16 xb AND x_skip passthrough (out1), 4 elems/thread.
// ---------------------------------------------------------------------------
__global__ __launch_bounds__(256) void cvt_x(const float* __restrict__ x,
                                             short* __restrict__ xb,
                                             float* __restrict__ out1) {
  int i = (blockIdx.x * 256 + threadIdx.x) * 4;
  f32x4 v = *(const f32x4*)(x + i);
  bf16x4 o;
  o[0] = f2s(v[0]); o[1] = f2s(v[1]); o[2] = f2s(v[2]); o[3] = f2s(v[3]);
  *(bf16x4*)(xb + i) = o;
  *(f32x4*)(out1 + i) = v;
}

// ---------------------------------------------------------------------------
// Weight prep: ipw(512x128)->bf16 (ws), x_proj_w -> wxb (64x256 bf16, rows
// 40..63 zero; staged in out0 -- safe: od_k writes out0 LAST, after wxb use).
// ---------------------------------------------------------------------------
__global__ __launch_bounds__(256) void prep_w(const float* __restrict__ ipw,
                                              const float* __restrict__ xpw,
                                              short* __restrict__ ipwb,
                                              short* __restrict__ wxb) {
  int idx = blockIdx.x * 256 + threadIdx.x;   // 0 .. 81919
  if (idx < 65536) {
    ipwb[idx] = f2s(ipw[idx]);
  } else {
    int j = idx - 65536;          // n*256 + k
    int n = j >> 8;
    wxb[j] = (n < 40) ? f2s(xpw[j]) : (short)0;
  }
}

// ---------------------------------------------------------------------------
// g_prep: fused tail weight G_k[co,e] = sum_dm dwn[co,dm,k] * opw[dm,e].
// Block = (k*128+co), 256 thr = e. fp32 dot, bf16 store. 12.6 MFLOP, tiny.
// G lives in the ipwb tail region (ipwb dead after in_proj; launched after).
// ---------------------------------------------------------------------------
__global__ __launch_bounds__(256) void g_prep(const float* __restrict__ dwn,
                                              const float* __restrict__ opw,
                                              short* __restrict__ G) {
  const int k  = blockIdx.x >> 7;
  const int co = blockIdx.x & 127;
  const int e  = threadIdx.x;
  float acc = 0.f;
  for (int dm = 0; dm < 128; ++dm) {
    acc += dwn[(co * 128 + dm) * 3 + k] * opw[dm * 256 + e];
  }
  G[(size_t)(k * 128 + co) * 256 + e] = f2s(acc);
}

// ---------------------------------------------------------------------------
// inproj_k: in_proj MFMA (M=32768 bt, N=512, K=128) with TRANSPOSED output.
// Block 256thr/4 waves, tile 64m x 64n. Epilogue: C-frags (+silu for z half)
// -> LDS LT[d_local][t_local] (scalar, ~4-way bank ok) -> coalesced b128
// stores to xcpreT / zT in (b,d,t). A block's 64 rows share one b; its 64
// cols are entirely in the xc half (n_base<256) or the z half.
// ---------------------------------------------------------------------------
__global__ __launch_bounds__(256) void inproj_k(const short* __restrict__ A,
                                                const short* __restrict__ W,
                                                short* __restrict__ xcpreT,
                                                short* __restrict__ zTb) {
  const int m_base = blockIdx.x * 64;
  const int n_base = blockIdx.y * 64;
  const int wave = threadIdx.x >> 6;
  const int lane = threadIdx.x & 63;
  const int r16  = lane & 15;
  const int quad = lane >> 4;
  f32x4 acc[4] = {};
  const short* Ap = A + (size_t)(m_base + wave * 16 + r16) * 128 + quad * 8;
  const short* Wp = W + (size_t)(n_base + r16) * 128 + quad * 8;
#pragma unroll
  for (int k0 = 0; k0 < 128; k0 += 32) {
    bf16x8 a = *(const bf16x8*)(Ap + k0);
#pragma unroll
    for (int j = 0; j < 4; ++j) {
      bf16x8 b = *(const bf16x8*)(Wp + (size_t)j * 16 * 128 + k0);
      acc[j] = __builtin_amdgcn_mfma_f32_16x16x32_bf16(a, b, acc[j], 0, 0, 0);
    }
  }
  __shared__ short LT[64][72];                 // [d_local][t_local], pad 8
  const bool isz = (n_base >= 256);
#pragma unroll
  for (int j = 0; j < 4; ++j) {
#pragma unroll
    for (int r = 0; r < 4; ++r) {
      float v = acc[j][r];
      short s = isz ? f2s(v / (1.f + __expf(-v))) : f2s(v);
      LT[j * 16 + r16][wave * 16 + quad * 4 + r] = s;
    }
  }
  __syncthreads();
  const int bb = m_base >> 8;
  const int tbase = m_base & 255;
  short* dst = isz ? zTb : xcpreT;
  const int dbase = isz ? (n_base - 256) : n_base;
#pragma unroll
  for (int it = 0; it < 2; ++it) {
    const int dw = (threadIdx.x >> 3) + it * 32;
    const int tc = (threadIdx.x & 7) * 8;
    bf16x8 v = *(const bf16x8*)(&LT[dw][tc]);
    *(bf16x8*)(dst + (size_t)(bb * 256 + dbase + dw) * 256 + tbase + tc) = v;
  }
}

// ---------------------------------------------------------------------------
// mid_k v2: fused depthwise conv+silu + x_proj MFMA + delta(softplus).
// Block = (b, 32-t eighth); 1024 blocks x 256 thr; LDS 17.9KB -> 4 blocks/CU.
//  phase 1: thread (tg of 4 x 8t, dl of 64) x 4 d-tiles: conv from xcpreT
//           (b,d,t) via 2 bf16x8 vector loads (cur + halo); out -> xcT direct
//           (regs) + XC[t][d] LDS scalar.
//  phase 2: x_proj MFMA M=32 N=48(used 40) K=256; waves 0..2 each one
//           16-col n-tile x 2 m-tiles. dt cols->DTL; B/C cols->SBC fp32.
//  phase 3: delta = softplus(dt . dtw[d] + dtb[d]) -> dT (b,d,t), vector out.
// ---------------------------------------------------------------------------
__global__ __launch_bounds__(256, 4) void mid_k(const short* __restrict__ xcpreT,
                                                const float* __restrict__ cw,
                                                const float* __restrict__ cb,
                                                const short* __restrict__ wxb,
                                                const float* __restrict__ dtw,
                                                const float* __restrict__ dtb,
                                                short* __restrict__ xcT,
                                                short* __restrict__ dT,
                                                float* __restrict__ SBC) {
  const int b  = blockIdx.x >> 3;
  const int t0 = (blockIdx.x & 7) * 32;       // t-eighth base
  const int tg = threadIdx.x >> 6;            // 4 groups of 8 t
  const int dl = threadIdx.x & 63;
  const int tA = t0 + tg * 8;
  __shared__ short XC[32][264];               // [t-local][d] bf16, pad 8
  __shared__ float DTL[32][8];                // dt cols per t-local
  // ---- phase 1: conv+silu, 4 d-tiles x 8 t per thread, vector loads ----
#pragma unroll
  for (int dtile = 0; dtile < 4; ++dtile) {
    const int d = dtile * 64 + dl;
    const float w0 = cw[d * 4], w1 = cw[d * 4 + 1];
    const float w2 = cw[d * 4 + 2], w3 = cw[d * 4 + 3];
    const float bias = cb[d];
    const size_t base = ((size_t)b * 256 + d) * 256;   // t-row base
    bf16x8 v = *(const bf16x8*)(xcpreT + base + tA);
    bf16x8 hp = {};
    if (tA >= 8) hp = *(const bf16x8*)(xcpreT + base + tA - 8);
    float x3 = s2f(hp[5]), x2 = s2f(hp[6]), x1 = s2f(hp[7]);
    bf16x8 outv;
#pragma unroll
    for (int i = 0; i < 8; ++i) {
      const float cur = s2f(v[i]);
      const float a = bias + x3 * w0 + x2 * w1 + x1 * w2 + cur * w3;
      const short s = f2s(a / (1.f + __expf(-a)));
      outv[i] = s;
      XC[tg * 8 + i][d] = s;
      x3 = x2; x2 = x1; x1 = cur;
    }
    *(bf16x8*)(xcT + base + tA) = outv;
  }
  __syncthreads();
  // ---- phase 2: x_proj MFMA (A = XC, W = wxb), waves 0..2 ----
  if (tg < 3) {
    const int r16  = dl & 15;
    const int quad = dl >> 4;
    f32x4 acc0 = {}, acc1 = {};
    const short* Wp = wxb + (size_t)(tg * 16 + r16) * 256 + quad * 8;
#pragma unroll
    for (int k0 = 0; k0 < 256; k0 += 32) {
      bf16x8 bb = *(const bf16x8*)(Wp + k0);
      bf16x8 a0 = *(const bf16x8*)(&XC[r16][quad * 8 + k0]);
      bf16x8 a1 = *(const bf16x8*)(&XC[16 + r16][quad * 8 + k0]);
      acc0 = __builtin_amdgcn_mfma_f32_16x16x32_bf16(a0, bb, acc0, 0, 0, 0);
      acc1 = __builtin_amdgcn_mfma_f32_16x16x32_bf16(a1, bb, acc1, 0, 0, 0);
    }
    const int col = tg * 16 + r16;
#pragma unroll
    for (int r = 0; r < 4; ++r) {
      const int tl0 = quad * 4 + r;
      const int tl1 = 16 + quad * 4 + r;
      if (col < 8) {
        DTL[tl0][col] = acc0[r];
        DTL[tl1][col] = acc1[r];
      } else if (col < 40) {
        SBC[((size_t)b * 256 + t0 + tl0) * 32 + (col - 8)] = acc0[r];
        SBC[((size_t)b * 256 + t0 + tl1) * 32 + (col - 8)] = acc1[r];
      }
    }
  }
  __syncthreads();
  // ---- phase 3: delta = softplus(dt . dtw + dtb) -> dT ----
#pragma unroll
  for (int dtile = 0; dtile < 4; ++dtile) {
    const int d = dtile * 64 + dl;
    float wd[8];
#pragma unroll
    for (int j = 0; j < 8; ++j) wd[j] = dtw[d * 8 + j];
    const float bd = dtb[d];
    const size_t base = ((size_t)b * 256 + d) * 256;
    bf16x8 dv;
#pragma unroll
    for (int i = 0; i < 8; ++i) {
      const int tl = tg * 8 + i;
      const f32x4 p0 = *(const f32x4*)(&DTL[tl][0]);
      const f32x4 p1 = *(const f32x4*)(&DTL[tl][4]);
      float acc = bd;
#pragma unroll
      for (int j = 0; j < 4; ++j) acc += p0[j] * wd[j] + p1[j] * wd[4 + j];
      const float delta = (acc > 20.f) ? acc : __logf(1.f + __expf(acc));
      dv[i] = f2s(delta);
    }
    *(bf16x8*)(dT + base + tA) = dv;
  }
}

// ---------------------------------------------------------------------------
// scan6 (R1 form, 62us): state-parallel selective scan, register-pipelined.
// Block = (b, group of 32 d), 128 thr = 32 d x 4 lanes; lane owns 4 of 16
// states, serial T=256. S (B/C fp32, LDS) chunk loads named-double-buffered;
// u/delta/z chunk dbuf; zT load exec-masked q==0; exp2 with log2e in A.
// S-fill reads dense SBC (b,t,32) fp32 -- fully coalesced.
// ---------------------------------------------------------------------------
#define SC6_PREFETCH(BUF, CH) do {                                           \
    _Pragma("unroll")                                                        \
    for (int j_ = 0; j_ < 8; ++j_) {                                         \
      SBr[BUF][j_] = *(const f32x4*)(&S[(CH) * 8 + j_][q * 4]);              \
      SCr[BUF][j_] = *(const f32x4*)(&S[(CH) * 8 + j_][16 + q * 4]);         \
    }                                                                        \
    uu[BUF] = *(const bf16x8*)(xcT + tb + (CH) * 8);                         \
    dd[BUF] = *(const bf16x8*)(dT + tb + (CH) * 8);                          \
    if (q == 0) zz[BUF] = *(const bf16x8*)(zT + tb + (CH) * 8);              \
  } while (0)

#define SC6_COMPUTE(BUF, CH) do {                                            \
    _Pragma("unroll")                                                        \
    for (int tt_ = 0; tt_ < 8; ++tt_) {                                      \
      const int t_ = (CH) * 8 + tt_;                                         \
      const float delta_ = s2f(dd[BUF][tt_]);                                \
      const float u_ = s2f(uu[BUF][tt_]);                                    \
      const float du_ = delta_ * u_;                                         \
      const f32x4 Bq_ = SBr[BUF][tt_];                                       \
      const f32x4 Cq_ = SCr[BUF][tt_];                                       \
      float yt_ = 0.f;                                                       \
      _Pragma("unroll")                                                      \
      for (int n_ = 0; n_ < 4; ++n_) {                                       \
        const float dA_ = __builtin_amdgcn_exp2f(delta_ * A2[n_]);           \
        h[n_] = dA_ * h[n_] + du_ * Bq_[n_];                                 \
        yt_ += h[n_] * Cq_[n_];                                              \
      }                                                                      \
      yt_ += __shfl_xor(yt_, 1);                                             \
      yt_ += __shfl_xor(yt_, 2);                                             \
      if (q == 0)                                                            \
        yb[(rb + t_) * 256 + d] = f2s((yt_ + u_ * Dv) * s2f(zz[BUF][tt_]));  \
    }                                                                        \
  } while (0)

__global__ __launch_bounds__(128, 2) void scan6(const float* __restrict__ SBC,
                                                const short* __restrict__ xcT,
                                                const short* __restrict__ dT,
                                                const short* __restrict__ zT,
                                                const float* __restrict__ alog,
                                                const float* __restrict__ Dp,
                                                short* __restrict__ yb) {
  const int g = blockIdx.x & 7;
  const int b = blockIdx.x >> 3;
  const int q = threadIdx.x & 3;
  const int d = g * 32 + (threadIdx.x >> 2);
  const size_t rb = (size_t)b * 256;
  __shared__ float S[256][32];                // B(16)|C(16) fp32 per t, 32 KB
  for (int i = threadIdx.x; i < 2048; i += 128) {
    *(f32x4*)(&S[i >> 3][(i & 7) * 4]) =
        *(const f32x4*)(SBC + (size_t)b * 8192 + i * 4);
  }
  float A2[4];
#pragma unroll
  for (int n = 0; n < 4; ++n)
    A2[n] = -__expf(alog[d * 16 + q * 4 + n]) * 1.44269504089f;
  const float Dv = Dp[d];
  float h[4] = {0.f, 0.f, 0.f, 0.f};
  const size_t tb = ((size_t)b * 256 + d) * 256;   // t-row base (b,d,t)
  f32x4 SBr[2][8], SCr[2][8];
  bf16x8 uu[2], dd[2];
  bf16x8 zz[2] = {};
  uu[0] = *(const bf16x8*)(xcT + tb);
  dd[0] = *(const bf16x8*)(dT + tb);
  if (q == 0) zz[0] = *(const bf16x8*)(zT + tb);
  __syncthreads();
#pragma unroll
  for (int j_ = 0; j_ < 8; ++j_) {
    SBr[0][j_] = *(const f32x4*)(&S[j_][q * 4]);
    SCr[0][j_] = *(const f32x4*)(&S[j_][16 + q * 4]);
  }
  for (int c = 0; c < 32; c += 2) {
    SC6_PREFETCH(1, c + 1);
    SC6_COMPUTE(0, c);
    if (c + 2 < 32) SC6_PREFETCH(0, c + 2);
    SC6_COMPUTE(1, c + 1);
  }
}

// ---------------------------------------------------------------------------
// od_k: fused out_proj + strided down-conv + bias + LayerNorm.
//   pre[b,to,co] = sum_{k=0..2} yb[b, 2to+k-1, :] . G_k[co, :]  + db[co]
//   out = LN(pre) over co (128), eps 1e-5.
// Grid 256 blocks x 256 thr (4 waves x 16 m-rows); m = b*128+to. K=768 via
// 3 row-shifted K=256 segments. G is 196KB -> L2-resident. LN fused: 16-lane
// shfl_xor reductions.
// ---------------------------------------------------------------------------
__global__ __launch_bounds__(256) void od_k(const short* __restrict__ yb,
                                            const short* __restrict__ G,
                                            const float* __restrict__ db,
                                            const float* __restrict__ lng,
                                            const float* __restrict__ lnb,
                                            float* __restrict__ out) {
  const int wave = threadIdx.x >> 6;
  const int lane = threadIdx.x & 63;
  const int r16  = lane & 15;
  const int quad = lane >> 4;
  const int m_base = blockIdx.x * 64 + wave * 16;
  const int ma = m_base + r16;
  const int ba = ma >> 7, toa = ma & 127;
  f32x4 acc[8] = {};
  const bf16x8 az = {};
#pragma unroll
  for (int k = 0; k < 3; ++k) {
    const int tp = 2 * toa + k - 1;
    const bool valid = (tp >= 0) && (tp < 256);
    const int tpc = tp < 0 ? 0 : (tp > 255 ? 255 : tp);
    const short* Ap = yb + (size_t)(ba * 256 + tpc) * 256 + quad * 8;
    const short* Gp = G + (size_t)(k * 128 + r16) * 256 + quad * 8;
#pragma unroll
    for (int k0 = 0; k0 < 256; k0 += 32) {
      bf16x8 a = *(const bf16x8*)(Ap + k0);
      a = valid ? a : az;
#pragma unroll
      for (int j = 0; j < 8; ++j) {
        bf16x8 g = *(const bf16x8*)(Gp + (size_t)j * 16 * 256 + k0);
        acc[j] = __builtin_amdgcn_mfma_f32_16x16x32_bf16(a, g, acc[j], 0, 0, 0);
      }
    }
  }
  float dbv[8], g8[8], be8[8];
#pragma unroll
  for (int j = 0; j < 8; ++j) {
    const int col = j * 16 + r16;
    dbv[j] = db[col]; g8[j] = lng[col]; be8[j] = lnb[col];
  }
#pragma unroll
  for (int r = 0; r < 4; ++r) {
    float v[8];
    float s = 0.f;
#pragma unroll
    for (int j = 0; j < 8; ++j) { v[j] = acc[j][r] + dbv[j]; s += v[j]; }
    s += __shfl_xor(s, 1); s += __shfl_xor(s, 2);
    s += __shfl_xor(s, 4); s += __shfl_xor(s, 8);
    const float mu = s * (1.0f / 128.0f);
    float vs = 0.f;
#pragma unroll
    for (int j = 0; j < 8; ++j) { const float dd = v[j] - mu; vs += dd * dd; }
    vs += __shfl_xor(vs, 1); vs += __shfl_xor(vs, 2);
    vs += __shfl_xor(vs, 4); vs += __shfl_xor(vs, 8);
    const float rstd = rsqrtf(vs * (1.0f / 128.0f) + 1e-5f);
    const int rowm = m_base + quad * 4 + r;
#pragma unroll
    for (int j = 0; j < 8; ++j) {
      out[(size_t)rowm * 128 + j * 16 + r16] = (v[j] - mu) * rstd * g8[j] + be8[j];
    }
  }
}

// ---------------------------------------------------------------------------
// Workspace layout (bytes), peak 92,471,296 == proven-safe bound:
//   [0,16M)      xcpreT bf16 (inproj->mid_k) -> yb bf16 (scan->od_k)
//   [16M,32M)    xcT bf16 (mid_k->scan)
//   [32M,48M)    zT bf16 (inproj->scan)
//   [48M,64M)    dT bf16 (mid_k->scan)
//   [64M,68.2M)  SBC fp32 4MB (mid_k->scan)
//   [72M,80.4M)  xb bf16 8.4MB (cvt->inproj)
//   [88M,88.2M)  ipwb bf16 131,072B (prep->inproj) -> G bf16 196,608B
//                (g_prep->od_k; launched AFTER inproj consumed ipwb;
//                 region ends exactly at 92,471,296)
// d_out staging: wxb (32KB bf16) at out0 base (od_k writes out0 LAST);
// out1 written once by cvt_x.
// ---------------------------------------------------------------------------
static const size_t O_XCPRE = 0;            // also yb
static const size_t O_XCT   = 16777216;
static const size_t O_ZT    = 33554432;
static const size_t O_DT    = 50331648;
static const size_t O_SBC   = 67108864;
static const size_t O_XB    = 75497472;
static const size_t O_IPWB  = 92274688;     // 131,072 B; then G 196,608 B

extern "C" void kernel_launch(void* const* d_in, const int* in_sizes, int n_in,
                              void* d_out, int out_size, void* d_ws, size_t ws_size,
                              hipStream_t stream) {
  const float* x    = (const float*)d_in[0];
  const float* ipw  = (const float*)d_in[1];
  const float* cw   = (const float*)d_in[2];
  const float* cb   = (const float*)d_in[3];
  const float* xpw  = (const float*)d_in[4];
  const float* dtw  = (const float*)d_in[5];
  const float* dtb  = (const float*)d_in[6];
  const float* alog = (const float*)d_in[7];
  const float* Dp   = (const float*)d_in[8];
  const float* opw  = (const float*)d_in[9];
  const float* dw   = (const float*)d_in[10];
  const float* db   = (const float*)d_in[11];
  const float* lng  = (const float*)d_in[12];
  const float* lnb  = (const float*)d_in[13];

  char*  ws     = (char*)d_ws;
  short* xcpreT = (short*)(ws + O_XCPRE);
  short* yb     = (short*)(ws + O_XCPRE);  // alias (xcpreT dead after mid_k)
  short* xcT    = (short*)(ws + O_XCT);
  short* zT     = (short*)(ws + O_ZT);
  short* dT     = (short*)(ws + O_DT);
  float* SBC    = (float*)(ws + O_SBC);
  short* xb     = (short*)(ws + O_XB);
  short* ipwb   = (short*)(ws + O_IPWB);
  short* G      = (short*)(ws + O_IPWB);   // alias (ipwb dead after inproj)
  float* out    = (float*)d_out;
  short* wxb    = (short*)out;             // out0 staging; od_k writes last
  float* out1   = out + 2097152;

  // 0. x -> bf16 + x_skip passthrough; weight prep
  cvt_x<<<4096, 256, 0, stream>>>(x, xb, out1);
  prep_w<<<320, 256, 0, stream>>>(ipw, xpw, ipwb, wxb);
  // 1. in_proj MFMA -> TRANSPOSED xcpreT (b,d,t) + zT (b,d,t) via LDS tile
  inproj_k<<<dim3(512, 8), 256, 0, stream>>>(xb, ipwb, xcpreT, zT);
  // 2. fused tail weight G_k = dwn_k @ opw (overwrites ipwb -- consumed)
  g_prep<<<384, 256, 0, stream>>>(dw, opw, G);
  // 3. fused conv+silu + x_proj + delta (vector loads, 4 blocks/CU)
  mid_k<<<1024, 256, 0, stream>>>(xcpreT, cw, cb, wxb, dtw, dtb,
                                  xcT, dT, SBC);
  // 4. state-parallel scan -> yb bf16
  scan6<<<1024, 128, 0, stream>>>(SBC, xcT, dT, zT, alog, Dp, yb);
  // 5. fused out_proj + down-conv + bias + LayerNorm -> output 0
  od_k<<<256, 256, 0, stream>>>(yb, G, db, lng, lnb, out);
}

// Round 6
// 251.712 us; speedup vs baseline: 1.3865x; 1.0169x over previous
//
#include <hip/hip_runtime.h>
#include <hip/hip_bf16.h>

// Problem dims (fixed by reference)
//   B=128, T=256, D_MODEL=128, D_INNER=256, D_STATE=16, D_CONV=4, DT_RANK=8
// I/O dtype: float32. MFMA bf16 for in_proj/x_proj/fused-tail. R17:
//  - scan8 = scan6 + REGISTER PINNING: every prefetched value (16 ds_read_b128
//    of S + u/d/z) is pinned with asm volatile("" : "+v"(x)) right after its
//    load. R12/R5 showed the LLVM scheduler sinks the S-chunk loads to
//    point-of-use (VGPR stayed 92, not ~220) to cut register pressure; the
//    empty asm forces materialization at the prefetch point, making the
//    double-buffer real. At 2 waves/SIMD (grid-capped) the +128 VGPR is free.
//  - Everything else identical to R16 (255.97us).
// Outputs: h (128,128,128) then x_skip (128,256,128), fp32, concatenated.

typedef __attribute__((ext_vector_type(8))) short bf16x8;
typedef __attribute__((ext_vector_type(4))) short bf16x4;
typedef __attribute__((ext_vector_type(4))) float f32x4;
using bf16 = __hip_bfloat16;

static __device__ __forceinline__ short f2s(float v) {
  union { bf16 b; short s; } u; u.b = (bf16)v; return u.s;
}
static __device__ __forceinline__ float s2f(short s) {
  union { short s; bf16 b; } u; u.s = s; return (float)u.b;
}

// ---------------------------------------------------------------------------
// cvt_x: x fp32 -> bf16 xb AND x_skip passthrough (out1), 4 elems/thread.
// ---------------------------------------------------------------------------
__global__ __launch_bounds__(256) void cvt_x(const float* __restrict__ x,
                                             short* __restrict__ xb,
                                             float* __restrict__ out1) {
  int i = (blockIdx.x * 256 + threadIdx.x) * 4;
  f32x4 v = *(const f32x4*)(x + i);
  bf16x4 o;
  o[0] = f2s(v[0]); o[1] = f2s(v[1]); o[2] = f2s(v[2]); o[3] = f2s(v[3]);
  *(bf16x4*)(xb + i) = o;
  *(f32x4*)(out1 + i) = v;
}

// ---------------------------------------------------------------------------
// Weight prep: ipw(512x128)->bf16 (ws), x_proj_w -> wxb (64x256 bf16, rows
// 40..63 zero; staged in out0 -- safe: od_k writes out0 LAST, after wxb use).
// ---------------------------------------------------------------------------
__global__ __launch_bounds__(256) void prep_w(const float* __restrict__ ipw,
                                              const float* __restrict__ xpw,
                                              short* __restrict__ ipwb,
                                              short* __restrict__ wxb) {
  int idx = blockIdx.x * 256 + threadIdx.x;   // 0 .. 81919
  if (idx < 65536) {
    ipwb[idx] = f2s(ipw[idx]);
  } else {
    int j = idx - 65536;          // n*256 + k
    int n = j >> 8;
    wxb[j] = (n < 40) ? f2s(xpw[j]) : (short)0;
  }
}

// ---------------------------------------------------------------------------
// g_prep: fused tail weight G_k[co,e] = sum_dm dwn[co,dm,k] * opw[dm,e].
// Block = (k*128+co), 256 thr = e. fp32 dot, bf16 store. 12.6 MFLOP, tiny.
// G lives in the ipwb tail region (ipwb dead after in_proj; launched after).
// ---------------------------------------------------------------------------
__global__ __launch_bounds__(256) void g_prep(const float* __restrict__ dwn,
                                              const float* __restrict__ opw,
                                              short* __restrict__ G) {
  const int k  = blockIdx.x >> 7;
  const int co = blockIdx.x & 127;
  const int e  = threadIdx.x;
  float acc = 0.f;
  for (int dm = 0; dm < 128; ++dm) {
    acc += dwn[(co * 128 + dm) * 3 + k] * opw[dm * 256 + e];
  }
  G[(size_t)(k * 128 + co) * 256 + e] = f2s(acc);
}

// ---------------------------------------------------------------------------
// inproj_k: in_proj MFMA (M=32768 bt, N=512, K=128) with TRANSPOSED output.
// Block 256thr/4 waves, tile 64m x 64n. Epilogue: C-frags (+silu for z half)
// -> LDS LT[d_local][t_local] (scalar, ~4-way bank ok) -> coalesced b128
// stores to xcpreT / zT in (b,d,t). A block's 64 rows share one b; its 64
// cols are entirely in the xc half (n_base<256) or the z half.
// ---------------------------------------------------------------------------
__global__ __launch_bounds__(256) void inproj_k(const short* __restrict__ A,
                                                const short* __restrict__ W,
                                                short* __restrict__ xcpreT,
                                                short* __restrict__ zTb) {
  const int m_base = blockIdx.x * 64;
  const int n_base = blockIdx.y * 64;
  const int wave = threadIdx.x >> 6;
  const int lane = threadIdx.x & 63;
  const int r16  = lane & 15;
  const int quad = lane >> 4;
  f32x4 acc[4] = {};
  const short* Ap = A + (size_t)(m_base + wave * 16 + r16) * 128 + quad * 8;
  const short* Wp = W + (size_t)(n_base + r16) * 128 + quad * 8;
#pragma unroll
  for (int k0 = 0; k0 < 128; k0 += 32) {
    bf16x8 a = *(const bf16x8*)(Ap + k0);
#pragma unroll
    for (int j = 0; j < 4; ++j) {
      bf16x8 b = *(const bf16x8*)(Wp + (size_t)j * 16 * 128 + k0);
      acc[j] = __builtin_amdgcn_mfma_f32_16x16x32_bf16(a, b, acc[j], 0, 0, 0);
    }
  }
  __shared__ short LT[64][72];                 // [d_local][t_local], pad 8
  const bool isz = (n_base >= 256);
#pragma unroll
  for (int j = 0; j < 4; ++j) {
#pragma unroll
    for (int r = 0; r < 4; ++r) {
      float v = acc[j][r];
      short s = isz ? f2s(v / (1.f + __expf(-v))) : f2s(v);
      LT[j * 16 + r16][wave * 16 + quad * 4 + r] = s;
    }
  }
  __syncthreads();
  const int bb = m_base >> 8;
  const int tbase = m_base & 255;
  short* dst = isz ? zTb : xcpreT;
  const int dbase = isz ? (n_base - 256) : n_base;
#pragma unroll
  for (int it = 0; it < 2; ++it) {
    const int dw = (threadIdx.x >> 3) + it * 32;
    const int tc = (threadIdx.x & 7) * 8;
    bf16x8 v = *(const bf16x8*)(&LT[dw][tc]);
    *(bf16x8*)(dst + (size_t)(bb * 256 + dbase + dw) * 256 + tbase + tc) = v;
  }
}

// ---------------------------------------------------------------------------
// mid_k v2: fused depthwise conv+silu + x_proj MFMA + delta(softplus).
// Block = (b, 32-t eighth); 1024 blocks x 256 thr; LDS 17.9KB -> 4 blocks/CU.
//  phase 1: thread (tg of 4 x 8t, dl of 64) x 4 d-tiles: conv from xcpreT
//           (b,d,t) via 2 bf16x8 vector loads (cur + halo); out -> xcT direct
//           (regs) + XC[t][d] LDS scalar.
//  phase 2: x_proj MFMA M=32 N=48(used 40) K=256; waves 0..2 each one
//           16-col n-tile x 2 m-tiles. dt cols->DTL; B/C cols->SBC fp32.
//  phase 3: delta = softplus(dt . dtw[d] + dtb[d]) -> dT (b,d,t), vector out.
// ---------------------------------------------------------------------------
__global__ __launch_bounds__(256, 4) void mid_k(const short* __restrict__ xcpreT,
                                                const float* __restrict__ cw,
                                                const float* __restrict__ cb,
                                                const short* __restrict__ wxb,
                                                const float* __restrict__ dtw,
                                                const float* __restrict__ dtb,
                                                short* __restrict__ xcT,
                                                short* __restrict__ dT,
                                                float* __restrict__ SBC) {
  const int b  = blockIdx.x >> 3;
  const int t0 = (blockIdx.x & 7) * 32;       // t-eighth base
  const int tg = threadIdx.x >> 6;            // 4 groups of 8 t
  const int dl = threadIdx.x & 63;
  const int tA = t0 + tg * 8;
  __shared__ short XC[32][264];               // [t-local][d] bf16, pad 8
  __shared__ float DTL[32][8];                // dt cols per t-local
  // ---- phase 1: conv+silu, 4 d-tiles x 8 t per thread, vector loads ----
#pragma unroll
  for (int dtile = 0; dtile < 4; ++dtile) {
    const int d = dtile * 64 + dl;
    const float w0 = cw[d * 4], w1 = cw[d * 4 + 1];
    const float w2 = cw[d * 4 + 2], w3 = cw[d * 4 + 3];
    const float bias = cb[d];
    const size_t base = ((size_t)b * 256 + d) * 256;   // t-row base
    bf16x8 v = *(const bf16x8*)(xcpreT + base + tA);
    bf16x8 hp = {};
    if (tA >= 8) hp = *(const bf16x8*)(xcpreT + base + tA - 8);
    float x3 = s2f(hp[5]), x2 = s2f(hp[6]), x1 = s2f(hp[7]);
    bf16x8 outv;
#pragma unroll
    for (int i = 0; i < 8; ++i) {
      const float cur = s2f(v[i]);
      const float a = bias + x3 * w0 + x2 * w1 + x1 * w2 + cur * w3;
      const short s = f2s(a / (1.f + __expf(-a)));
      outv[i] = s;
      XC[tg * 8 + i][d] = s;
      x3 = x2; x2 = x1; x1 = cur;
    }
    *(bf16x8*)(xcT + base + tA) = outv;
  }
  __syncthreads();
  // ---- phase 2: x_proj MFMA (A = XC, W = wxb), waves 0..2 ----
  if (tg < 3) {
    const int r16  = dl & 15;
    const int quad = dl >> 4;
    f32x4 acc0 = {}, acc1 = {};
    const short* Wp = wxb + (size_t)(tg * 16 + r16) * 256 + quad * 8;
#pragma unroll
    for (int k0 = 0; k0 < 256; k0 += 32) {
      bf16x8 bb = *(const bf16x8*)(Wp + k0);
      bf16x8 a0 = *(const bf16x8*)(&XC[r16][quad * 8 + k0]);
      bf16x8 a1 = *(const bf16x8*)(&XC[16 + r16][quad * 8 + k0]);
      acc0 = __builtin_amdgcn_mfma_f32_16x16x32_bf16(a0, bb, acc0, 0, 0, 0);
      acc1 = __builtin_amdgcn_mfma_f32_16x16x32_bf16(a1, bb, acc1, 0, 0, 0);
    }
    const int col = tg * 16 + r16;
#pragma unroll
    for (int r = 0; r < 4; ++r) {
      const int tl0 = quad * 4 + r;
      const int tl1 = 16 + quad * 4 + r;
      if (col < 8) {
        DTL[tl0][col] = acc0[r];
        DTL[tl1][col] = acc1[r];
      } else if (col < 40) {
        SBC[((size_t)b * 256 + t0 + tl0) * 32 + (col - 8)] = acc0[r];
        SBC[((size_t)b * 256 + t0 + tl1) * 32 + (col - 8)] = acc1[r];
      }
    }
  }
  __syncthreads();
  // ---- phase 3: delta = softplus(dt . dtw + dtb) -> dT ----
#pragma unroll
  for (int dtile = 0; dtile < 4; ++dtile) {
    const int d = dtile * 64 + dl;
    float wd[8];
#pragma unroll
    for (int j = 0; j < 8; ++j) wd[j] = dtw[d * 8 + j];
    const float bd = dtb[d];
    const size_t base = ((size_t)b * 256 + d) * 256;
    bf16x8 dv;
#pragma unroll
    for (int i = 0; i < 8; ++i) {
      const int tl = tg * 8 + i;
      const f32x4 p0 = *(const f32x4*)(&DTL[tl][0]);
      const f32x4 p1 = *(const f32x4*)(&DTL[tl][4]);
      float acc = bd;
#pragma unroll
      for (int j = 0; j < 4; ++j) acc += p0[j] * wd[j] + p1[j] * wd[4 + j];
      const float delta = (acc > 20.f) ? acc : __logf(1.f + __expf(acc));
      dv[i] = f2s(delta);
    }
    *(bf16x8*)(dT + base + tA) = dv;
  }
}

// ---------------------------------------------------------------------------
// scan8: scan6 + register pinning. Block = (b, group of 32 d), 128 thr =
// 32 d x 4 lanes; lane owns 4 of 16 states, serial T=256. S (B/C fp32, LDS)
// chunk loads double-buffered in registers; asm volatile("" : "+v") pins
// force the ds_read/global_load results to materialize at the prefetch
// point (the scheduler otherwise sinks them to point-of-use -- R12/R5 showed
// VGPR stuck at 92). u/d/z chunk dbuf; zT exec-masked q==0; exp2 w/ log2e.
// 2 waves/SIMD grid cap -> 256-VGPR budget, pins cost nothing.
// ---------------------------------------------------------------------------
#define PIN4(x)  asm volatile("" : "+v"(x))

#define SC8_PREFETCH(BUF, CH) do {                                           \
    _Pragma("unroll")                                                        \
    for (int j_ = 0; j_ < 8; ++j_) {                                         \
      SBr[BUF][j_] = *(const f32x4*)(&S[(CH) * 8 + j_][q * 4]);              \
      SCr[BUF][j_] = *(const f32x4*)(&S[(CH) * 8 + j_][16 + q * 4]);         \
    }                                                                        \
    uu[BUF] = *(const bf16x8*)(xcT + tb + (CH) * 8);                         \
    dd[BUF] = *(const bf16x8*)(dT + tb + (CH) * 8);                          \
    if (q == 0) zz[BUF] = *(const bf16x8*)(zT + tb + (CH) * 8);              \
    _Pragma("unroll")                                                        \
    for (int j_ = 0; j_ < 8; ++j_) {                                         \
      PIN4(SBr[BUF][j_]); PIN4(SCr[BUF][j_]);                                \
    }                                                                        \
    PIN4(uu[BUF]); PIN4(dd[BUF]); PIN4(zz[BUF]);                             \
  } while (0)

#define SC8_COMPUTE(BUF, CH) do {                                            \
    _Pragma("unroll")                                                        \
    for (int tt_ = 0; tt_ < 8; ++tt_) {                                      \
      const int t_ = (CH) * 8 + tt_;                                         \
      const float delta_ = s2f(dd[BUF][tt_]);                                \
      const float u_ = s2f(uu[BUF][tt_]);                                    \
      const float du_ = delta_ * u_;                                         \
      const f32x4 Bq_ = SBr[BUF][tt_];                                       \
      const f32x4 Cq_ = SCr[BUF][tt_];                                       \
      float yt_ = 0.f;                                                       \
      _Pragma("unroll")                                                      \
      for (int n_ = 0; n_ < 4; ++n_) {                                       \
        const float dA_ = __builtin_amdgcn_exp2f(delta_ * A2[n_]);           \
        h[n_] = dA_ * h[n_] + du_ * Bq_[n_];                                 \
        yt_ += h[n_] * Cq_[n_];                                              \
      }                                                                      \
      yt_ += __shfl_xor(yt_, 1);                                             \
      yt_ += __shfl_xor(yt_, 2);                                             \
      if (q == 0)                                                            \
        yb[(rb + t_) * 256 + d] = f2s((yt_ + u_ * Dv) * s2f(zz[BUF][tt_]));  \
    }                                                                        \
  } while (0)

__global__ __launch_bounds__(128, 2) void scan8(const float* __restrict__ SBC,
                                                const short* __restrict__ xcT,
                                                const short* __restrict__ dT,
                                                const short* __restrict__ zT,
                                                const float* __restrict__ alog,
                                                const float* __restrict__ Dp,
                                                short* __restrict__ yb) {
  const int g = blockIdx.x & 7;
  const int b = blockIdx.x >> 3;
  const int q = threadIdx.x & 3;
  const int d = g * 32 + (threadIdx.x >> 2);
  const size_t rb = (size_t)b * 256;
  __shared__ float S[256][32];                // B(16)|C(16) fp32 per t, 32 KB
  for (int i = threadIdx.x; i < 2048; i += 128) {
    *(f32x4*)(&S[i >> 3][(i & 7) * 4]) =
        *(const f32x4*)(SBC + (size_t)b * 8192 + i * 4);
  }
  float A2[4];
#pragma unroll
  for (int n = 0; n < 4; ++n)
    A2[n] = -__expf(alog[d * 16 + q * 4 + n]) * 1.44269504089f;
  const float Dv = Dp[d];
  float h[4] = {0.f, 0.f, 0.f, 0.f};
  const size_t tb = ((size_t)b * 256 + d) * 256;   // t-row base (b,d,t)
  f32x4 SBr[2][8], SCr[2][8];
  bf16x8 uu[2], dd[2];
  bf16x8 zz[2] = {};
  // global chunk-0 loads can start before the LDS fill is visible
  uu[0] = *(const bf16x8*)(xcT + tb);
  dd[0] = *(const bf16x8*)(dT + tb);
  if (q == 0) zz[0] = *(const bf16x8*)(zT + tb);
  PIN4(uu[0]); PIN4(dd[0]); PIN4(zz[0]);
  __syncthreads();
#pragma unroll
  for (int j_ = 0; j_ < 8; ++j_) {
    SBr[0][j_] = *(const f32x4*)(&S[j_][q * 4]);
    SCr[0][j_] = *(const f32x4*)(&S[j_][16 + q * 4]);
    PIN4(SBr[0][j_]); PIN4(SCr[0][j_]);
  }
  for (int c = 0; c < 32; c += 2) {
    SC8_PREFETCH(1, c + 1);
    SC8_COMPUTE(0, c);
    if (c + 2 < 32) SC8_PREFETCH(0, c + 2);
    SC8_COMPUTE(1, c + 1);
  }
}

// ---------------------------------------------------------------------------
// od_k: fused out_proj + strided down-conv + bias + LayerNorm.
//   pre[b,to,co] = sum_{k=0..2} yb[b, 2to+k-1, :] . G_k[co, :]  + db[co]
//   out = LN(pre) over co (128), eps 1e-5.
// Grid 256 blocks x 256 thr (4 waves x 16 m-rows); m = b*128+to. K=768 via
// 3 row-shifted K=256 segments. G is 196KB -> L2-resident. LN fused: 16-lane
// shfl_xor reductions.
// ---------------------------------------------------------------------------
__global__ __launch_bounds__(256) void od_k(const short* __restrict__ yb,
                                            const short* __restrict__ G,
                                            const float* __restrict__ db,
                                            const float* __restrict__ lng,
                                            const float* __restrict__ lnb,
                                            float* __restrict__ out) {
  const int wave = threadIdx.x >> 6;
  const int lane = threadIdx.x & 63;
  const int r16  = lane & 15;
  const int quad = lane >> 4;
  const int m_base = blockIdx.x * 64 + wave * 16;
  const int ma = m_base + r16;
  const int ba = ma >> 7, toa = ma & 127;
  f32x4 acc[8] = {};
  const bf16x8 az = {};
#pragma unroll
  for (int k = 0; k < 3; ++k) {
    const int tp = 2 * toa + k - 1;
    const bool valid = (tp >= 0) && (tp < 256);
    const int tpc = tp < 0 ? 0 : (tp > 255 ? 255 : tp);
    const short* Ap = yb + (size_t)(ba * 256 + tpc) * 256 + quad * 8;
    const short* Gp = G + (size_t)(k * 128 + r16) * 256 + quad * 8;
#pragma unroll
    for (int k0 = 0; k0 < 256; k0 += 32) {
      bf16x8 a = *(const bf16x8*)(Ap + k0);
      a = valid ? a : az;
#pragma unroll
      for (int j = 0; j < 8; ++j) {
        bf16x8 g = *(const bf16x8*)(Gp + (size_t)j * 16 * 256 + k0);
        acc[j] = __builtin_amdgcn_mfma_f32_16x16x32_bf16(a, g, acc[j], 0, 0, 0);
      }
    }
  }
  float dbv[8], g8[8], be8[8];
#pragma unroll
  for (int j = 0; j < 8; ++j) {
    const int col = j * 16 + r16;
    dbv[j] = db[col]; g8[j] = lng[col]; be8[j] = lnb[col];
  }
#pragma unroll
  for (int r = 0; r < 4; ++r) {
    float v[8];
    float s = 0.f;
#pragma unroll
    for (int j = 0; j < 8; ++j) { v[j] = acc[j][r] + dbv[j]; s += v[j]; }
    s += __shfl_xor(s, 1); s += __shfl_xor(s, 2);
    s += __shfl_xor(s, 4); s += __shfl_xor(s, 8);
    const float mu = s * (1.0f / 128.0f);
    float vs = 0.f;
#pragma unroll
    for (int j = 0; j < 8; ++j) { const float dd = v[j] - mu; vs += dd * dd; }
    vs += __shfl_xor(vs, 1); vs += __shfl_xor(vs, 2);
    vs += __shfl_xor(vs, 4); vs += __shfl_xor(vs, 8);
    const float rstd = rsqrtf(vs * (1.0f / 128.0f) + 1e-5f);
    const int rowm = m_base + quad * 4 + r;
#pragma unroll
    for (int j = 0; j < 8; ++j) {
      out[(size_t)rowm * 128 + j * 16 + r16] = (v[j] - mu) * rstd * g8[j] + be8[j];
    }
  }
}

// ---------------------------------------------------------------------------
// Workspace layout (bytes), peak 92,471,296 == proven-safe bound:
//   [0,16M)      xcpreT bf16 (inproj->mid_k) -> yb bf16 (scan->od_k)
//   [16M,32M)    xcT bf16 (mid_k->scan)
//   [32M,48M)    zT bf16 (inproj->scan)
//   [48M,64M)    dT bf16 (mid_k->scan)
//   [64M,68.2M)  SBC fp32 4MB (mid_k->scan)
//   [72M,80.4M)  xb bf16 8.4MB (cvt->inproj)
//   [88M,88.2M)  ipwb bf16 131,072B (prep->inproj) -> G bf16 196,608B
//                (g_prep->od_k; launched AFTER inproj consumed ipwb;
//                 region ends exactly at 92,471,296)
// d_out staging: wxb (32KB bf16) at out0 base (od_k writes out0 LAST);
// out1 written once by cvt_x.
// ---------------------------------------------------------------------------
static const size_t O_XCPRE = 0;            // also yb
static const size_t O_XCT   = 16777216;
static const size_t O_ZT    = 33554432;
static const size_t O_DT    = 50331648;
static const size_t O_SBC   = 67108864;
static const size_t O_XB    = 75497472;
static const size_t O_IPWB  = 92274688;     // 131,072 B; then G 196,608 B

extern "C" void kernel_launch(void* const* d_in, const int* in_sizes, int n_in,
                              void* d_out, int out_size, void* d_ws, size_t ws_size,
                              hipStream_t stream) {
  const float* x    = (const float*)d_in[0];
  const float* ipw  = (const float*)d_in[1];
  const float* cw   = (const float*)d_in[2];
  const float* cb   = (const float*)d_in[3];
  const float* xpw  = (const float*)d_in[4];
  const float* dtw  = (const float*)d_in[5];
  const float* dtb  = (const float*)d_in[6];
  const float* alog = (const float*)d_in[7];
  const float* Dp   = (const float*)d_in[8];
  const float* opw  = (const float*)d_in[9];
  const float* dw   = (const float*)d_in[10];
  const float* db   = (const float*)d_in[11];
  const float* lng  = (const float*)d_in[12];
  const float* lnb  = (const float*)d_in[13];

  char*  ws     = (char*)d_ws;
  short* xcpreT = (short*)(ws + O_XCPRE);
  short* yb     = (short*)(ws + O_XCPRE);  // alias (xcpreT dead after mid_k)
  short* xcT    = (short*)(ws + O_XCT);
  short* zT     = (short*)(ws + O_ZT);
  short* dT     = (short*)(ws + O_DT);
  float* SBC    = (float*)(ws + O_SBC);
  short* xb     = (short*)(ws + O_XB);
  short* ipwb   = (short*)(ws + O_IPWB);
  short* G      = (short*)(ws + O_IPWB);   // alias (ipwb dead after inproj)
  float* out    = (float*)d_out;
  short* wxb    = (short*)out;             // out0 staging; od_k writes last
  float* out1   = out + 2097152;

  // 0. x -> bf16 + x_skip passthrough; weight prep
  cvt_x<<<4096, 256, 0, stream>>>(x, xb, out1);
  prep_w<<<320, 256, 0, stream>>>(ipw, xpw, ipwb, wxb);
  // 1. in_proj MFMA -> TRANSPOSED xcpreT (b,d,t) + zT (b,d,t) via LDS tile
  inproj_k<<<dim3(512, 8), 256, 0, stream>>>(xb, ipwb, xcpreT, zT);
  // 2. fused tail weight G_k = dwn_k @ opw (overwrites ipwb -- consumed)
  g_prep<<<384, 256, 0, stream>>>(dw, opw, G);
  // 3. fused conv+silu + x_proj + delta (vector loads, 4 blocks/CU)
  mid_k<<<1024, 256, 0, stream>>>(xcpreT, cw, cb, wxb, dtw, dtb,
                                  xcT, dT, SBC);
  // 4. state-parallel scan (register-pinned prefetch) -> yb bf16
  scan8<<<1024, 128, 0, stream>>>(SBC, xcT, dT, zT, alog, Dp, yb);
  // 5. fused out_proj + down-conv + bias + LayerNorm -> output 0
  od_k<<<256, 256, 0, stream>>>(yb, G, db, lng, lnb, out);
}